// Round 6
// baseline (1382.025 us; speedup 1.0000x reference)
//
#include <hip/hip_runtime.h>
#include <hip/hip_bf16.h>

// ---------------------------------------------------------------------------
// TransformerBlock: B=2 N=2048 E=2048 H=16 G=4 D=128 HID=8192
// out = [ x2 (8.39M f32) | k_flat (8.39M) | v_flat (8.39M) | attn (134.2M) ]
// R5 (re-run; R5 bench was lost to an infra failure): kattn v2 — 8 waves/block
// (512 thr), 256-key strips, 16 d-cols/wave in PV. Same 66KB LDS -> 2
// blocks/CU but 16 waves/CU (was 8): latency-bound fix per R4 counters
// (Occ 23.7%, MfmaUtil 5%, VALU 9.6%).
// ---------------------------------------------------------------------------

using f32x4  = __attribute__((ext_vector_type(4))) float;
using bf16x8 = __attribute__((ext_vector_type(8))) short;
using bf16x4 = __attribute__((ext_vector_type(4))) short;
using u16x4  = __attribute__((ext_vector_type(4))) unsigned short;

#define DEV __device__ __forceinline__

// async global->LDS, 16B per lane; LDS dest must be wave-uniform base + lane*16
#define ASYNC16(lds, g)                                                        \
  __builtin_amdgcn_global_load_lds(                                           \
      (const __attribute__((address_space(1))) void*)(g),                      \
      (__attribute__((address_space(3))) void*)(lds), 16, 0, 0)

DEV unsigned short f2bf(float f) {
  unsigned int u = __float_as_uint(f);
  return (unsigned short)((u + 0x7fffu + ((u >> 16) & 1u)) >> 16);
}
DEV float bf2f(unsigned short h) {
  return __uint_as_float(((unsigned int)h) << 16);
}

DEV float waveRedSum(float v) {
#pragma unroll
  for (int o = 32; o; o >>= 1) v += __shfl_xor(v, o);
  return v;
}

// ---- transpose+convert: in f32 [K,N] -> out bf16 [N,K] ---------------------
__global__ __launch_bounds__(256) void kconvT(const float* __restrict__ in,
                                              unsigned short* __restrict__ out,
                                              int K, int N) {
  __shared__ float tile[32][33];
  int bx = blockIdx.x * 32;  // N dim
  int by = blockIdx.y * 32;  // K dim
  int tx = threadIdx.x & 31;
  int ty = threadIdx.x >> 5;  // 0..7
#pragma unroll
  for (int i = 0; i < 32; i += 8)
    tile[ty + i][tx] = in[(size_t)(by + ty + i) * N + bx + tx];
  __syncthreads();
#pragma unroll
  for (int i = 0; i < 32; i += 8)
    out[(size_t)(bx + ty + i) * K + by + tx] = f2bf(tile[tx][ty + i]);
}

// ---- v_flat = x (f32 copy) and x_bf16 --------------------------------------
__global__ __launch_bounds__(256) void kcopy(const f32x4* __restrict__ x,
                                             f32x4* __restrict__ v,
                                             u16x4* __restrict__ xb) {
  int i = blockIdx.x * 256 + threadIdx.x;  // exactly 2,097,152 threads
  f32x4 val = x[i];
  v[i] = val;
  u16x4 o;
  o[0] = f2bf(val[0]); o[1] = f2bf(val[1]); o[2] = f2bf(val[2]); o[3] = f2bf(val[3]);
  xb[i] = o;
}

// ---- RoPE on per-head slices of x -> k_flat f32 (d_out) + xq bf16 ----------
__global__ __launch_bounds__(256) void krope(const float* __restrict__ x,
                                             float* __restrict__ kout,
                                             unsigned short* __restrict__ xq) {
  int idx = blockIdx.x * 256 + threadIdx.x;  // B*N*H*64 = 4,194,304
  int f  = idx & 63;
  int h  = (idx >> 6) & 15;
  int bn = idx >> 10;          // b*2048+n
  int n  = bn & 2047;
  size_t base = (size_t)bn * 2048 + h * 128;
  float inv = exp2f((float)f * (-13.287712379549449f / 64.0f));
  float ang = (float)n * inv;
  float c = cosf(ang), s = sinf(ang);
  float a = x[base + f], b = x[base + f + 64];
  float k1 = a * c - b * s;
  float k2 = b * c + a * s;
  kout[base + f]      = k1;
  kout[base + f + 64] = k2;
  xq[base + f]      = f2bf(k1);
  xq[base + f + 64] = f2bf(k2);
}

// ---- x1b = bf16(rmsnorm(x + ao) * w) ---------------------------------------
__global__ __launch_bounds__(256) void krms1(const float* __restrict__ x,
                                             const float* __restrict__ ao,
                                             const float* __restrict__ w,
                                             unsigned short* __restrict__ x1b) {
  size_t row = blockIdx.x;
  const f32x4* xp = (const f32x4*)(x + row * 2048);
  const f32x4* ap = (const f32x4*)(ao + row * 2048);
  int tid = threadIdx.x;
  f32x4 t0 = xp[tid * 2] + ap[tid * 2];
  f32x4 t1 = xp[tid * 2 + 1] + ap[tid * 2 + 1];
  float ss = 0.f;
#pragma unroll
  for (int i = 0; i < 4; ++i) ss += t0[i] * t0[i] + t1[i] * t1[i];
  ss = waveRedSum(ss);
  __shared__ float red[4];
  int wid = tid >> 6, lane = tid & 63;
  if (!lane) red[wid] = ss;
  __syncthreads();
  ss = red[0] + red[1] + red[2] + red[3];
  float rr = rsqrtf(ss * (1.0f / 2048.0f) + 1e-6f);
  const f32x4* wp = (const f32x4*)w;
  f32x4 w0 = wp[tid * 2], w1 = wp[tid * 2 + 1];
  u16x4 o0, o1;
#pragma unroll
  for (int i = 0; i < 4; ++i) {
    o0[i] = f2bf(t0[i] * rr * w0[i]);
    o1[i] = f2bf(t1[i] * rr * w1[i]);
  }
  u16x4* op = (u16x4*)(x1b + row * 2048);
  op[tid * 2] = o0;
  op[tid * 2 + 1] = o1;
}

// ---- x2 = f32(rmsnorm(x1b + fc) * w) -> d_out ------------------------------
__global__ __launch_bounds__(256) void krms2(const unsigned short* __restrict__ x1b,
                                             const unsigned short* __restrict__ fc,
                                             const float* __restrict__ w,
                                             float* __restrict__ out) {
  size_t row = blockIdx.x;
  const u16x4* xp = (const u16x4*)(x1b + row * 2048);
  const u16x4* fp = (const u16x4*)(fc + row * 2048);
  int tid = threadIdx.x;
  u16x4 a0 = xp[tid * 2], a1 = xp[tid * 2 + 1];
  u16x4 b0 = fp[tid * 2], b1 = fp[tid * 2 + 1];
  f32x4 t0, t1;
#pragma unroll
  for (int i = 0; i < 4; ++i) {
    t0[i] = bf2f(a0[i]) + bf2f(b0[i]);
    t1[i] = bf2f(a1[i]) + bf2f(b1[i]);
  }
  float ss = 0.f;
#pragma unroll
  for (int i = 0; i < 4; ++i) ss += t0[i] * t0[i] + t1[i] * t1[i];
  ss = waveRedSum(ss);
  __shared__ float red[4];
  int wid = tid >> 6, lane = tid & 63;
  if (!lane) red[wid] = ss;
  __syncthreads();
  ss = red[0] + red[1] + red[2] + red[3];
  float rr = rsqrtf(ss * (1.0f / 2048.0f) + 1e-6f);
  const f32x4* wp = (const f32x4*)w;
  f32x4 w0 = wp[tid * 2], w1 = wp[tid * 2 + 1];
  f32x4* op = (f32x4*)(out + row * 2048);
  op[tid * 2]     = t0 * rr * w0;
  op[tid * 2 + 1] = t1 * rr * w1;
}

// ---- 128x128 MFMA GEMM (small shapes: k/v projections) ---------------------
template <bool OUT_BF16, bool TRANS_OUT>
__global__ __launch_bounds__(256, 2) void gemm_bt(
    const unsigned short* __restrict__ A, const unsigned short* __restrict__ Bt,
    void* __restrict__ C_, int K, int lda, int ldb, int ldc, float alpha) {
  __shared__ unsigned short As[128 * 32];
  __shared__ unsigned short Bs[128 * 32];
  const int tid = threadIdx.x;
  const int bm0 = blockIdx.y * 128, bn0 = blockIdx.x * 128;

  f32x4 acc[4][4] = {};

  const int lane = tid & 63, wid = tid >> 6;
  const int wr = wid >> 1, wc = wid & 1;
  const int lr = lane & 15, kq = lane >> 4;
  const int srow = tid >> 2;        // 0..63
  const int scol = (tid & 3) * 8;   // 0,8,16,24
  unsigned short* AsW = As + tid * 8;
  unsigned short* BsW = Bs + tid * 8;

  for (int kt = 0; kt < K; kt += 32) {
    ASYNC16(AsW,        A + (size_t)(bm0 + srow)      * lda + kt + scol);
    ASYNC16(AsW + 2048, A + (size_t)(bm0 + srow + 64) * lda + kt + scol);
    ASYNC16(BsW,        Bt + (size_t)(bn0 + srow)      * ldb + kt + scol);
    ASYNC16(BsW + 2048, Bt + (size_t)(bn0 + srow + 64) * ldb + kt + scol);
    __syncthreads();
    bf16x8 afr[4], bfr[4];
#pragma unroll
    for (int i = 0; i < 4; ++i)
      afr[i] = *(const bf16x8*)&As[(wr * 64 + i * 16 + lr) * 32 + kq * 8];
#pragma unroll
    for (int j = 0; j < 4; ++j)
      bfr[j] = *(const bf16x8*)&Bs[(wc * 64 + j * 16 + lr) * 32 + kq * 8];
#pragma unroll
    for (int i = 0; i < 4; ++i)
#pragma unroll
      for (int j = 0; j < 4; ++j)
        acc[i][j] = __builtin_amdgcn_mfma_f32_16x16x32_bf16(afr[i], bfr[j],
                                                            acc[i][j], 0, 0, 0);
    __syncthreads();
  }

#pragma unroll
  for (int i = 0; i < 4; ++i)
#pragma unroll
    for (int j = 0; j < 4; ++j) {
      int rowb = bm0 + wr * 64 + i * 16 + kq * 4;
      int col = bn0 + wc * 64 + j * 16 + lr;
#pragma unroll
      for (int r = 0; r < 4; ++r) {
        float v = acc[i][j][r] * alpha;
        size_t idx = TRANS_OUT ? ((size_t)col * ldc + (rowb + r))
                               : ((size_t)(rowb + r) * ldc + col);
        if constexpr (OUT_BF16)
          ((unsigned short*)C_)[idx] = f2bf(v);
        else
          ((float*)C_)[idx] = v;
      }
    }
}

// ===========================================================================
// Fused attention v2: 8 waves/block (512 thr), 16 q-rows, 256-key strips.
// - swapped mfma(K,Q): lane holds P[key][q=lr] -> per-lane q-row softmax.
// - attn f32 write from regs; P bf16 -> LDS (XOR-swizzled 16B chunks).
// - PV: each wave does 16 d-cols over all 2048 keys (64 MFMA).
// - 66KB LDS -> 2 blocks/CU -> 16 waves/CU (4/SIMD) for latency hiding.
// ===========================================================================
__global__ __launch_bounds__(512, 4) void kattn(
    const unsigned short* __restrict__ qh,   // [b][n][h*128+d] ld 2048
    const unsigned short* __restrict__ kh,   // [b][n][g*128+d] ld 512
    const unsigned short* __restrict__ vT,   // [g*128+d][b*2048+key] ld 4096
    float* __restrict__ attn,                // [b][h][q][key]
    unsigned short* __restrict__ ctx) {      // [b][n][h*128+d] ld 2048
  __shared__ unsigned short P[16 * 2048];    // 64 KB
  __shared__ float redm[8][16], reds[8][16];
  const int tid = threadIdx.x;
  const int lane = tid & 63, w = tid >> 6;   // w 0..7
  const int lr = lane & 15, kq = lane >> 4;  // q = lr, k-quarter = kq
  const int z = blockIdx.y, bz = z >> 4, hz = z & 15;
  const int q0 = blockIdx.x * 16;

  // Q fragments (B-operand): Q[q=lr][k], k-contiguous
  const unsigned short* Aq =
      qh + ((size_t)(bz * 2048 + q0 + lr) * 2048 + hz * 128);
  bf16x8 qfr[4];
#pragma unroll
  for (int kk = 0; kk < 4; ++kk)
    qfr[kk] = *(const bf16x8*)(Aq + kk * 32 + kq * 8);

  // scores: C[key][q] = sum_k K[key][k] * Q[q][k]; wave strip = 256 keys
  const unsigned short* Bk =
      kh + ((size_t)(bz * 2048) * 512 + (hz >> 2) * 128);
  f32x4 acc[16];
#pragma unroll
  for (int j = 0; j < 16; ++j) acc[j] = f32x4{0.f, 0.f, 0.f, 0.f};
#pragma unroll
  for (int j = 0; j < 16; ++j) {
    const unsigned short* kp = Bk + (size_t)(w * 256 + j * 16 + lr) * 512;
#pragma unroll
    for (int kk = 0; kk < 4; ++kk) {
      bf16x8 kfr = *(const bf16x8*)(kp + kk * 32 + kq * 8);
      acc[j] = __builtin_amdgcn_mfma_f32_16x16x32_bf16(kfr, qfr[kk], acc[j],
                                                       0, 0, 0);
    }
  }

  // scale + row max (per-lane single q-row)
  const float scale = 0.08838834764831845f;
  float mx = -3.4e38f;
#pragma unroll
  for (int j = 0; j < 16; ++j) {
    acc[j] *= scale;
#pragma unroll
    for (int r = 0; r < 4; ++r) mx = fmaxf(mx, acc[j][r]);
  }
  mx = fmaxf(mx, __shfl_xor(mx, 16));
  mx = fmaxf(mx, __shfl_xor(mx, 32));
  if (kq == 0) redm[w][lr] = mx;
  __syncthreads();
  mx = redm[0][lr];
#pragma unroll
  for (int ww = 1; ww < 8; ++ww) mx = fmaxf(mx, redm[ww][lr]);

  // exp + row sum
  float sm = 0.f;
#pragma unroll
  for (int j = 0; j < 16; ++j) {
#pragma unroll
    for (int r = 0; r < 4; ++r) {
      float e = __expf(acc[j][r] - mx);
      acc[j][r] = e;
      sm += e;
    }
  }
  sm += __shfl_xor(sm, 16);
  sm += __shfl_xor(sm, 32);
  if (kq == 0) reds[w][lr] = sm;
  __syncthreads();
  float smt = reds[0][lr];
#pragma unroll
  for (int ww = 1; ww < 8; ++ww) smt += reds[ww][lr];
  float inv = 1.0f / smt;

  // write attn f32 + P bf16 to LDS (swizzled)
  float* arow = attn + (((size_t)z * 2048 + q0 + lr) * 2048);
#pragma unroll
  for (int j = 0; j < 16; ++j) {
    int key = w * 256 + j * 16 + kq * 4;
    f32x4 p = acc[j] * inv;
    *(f32x4*)(arow + key) = p;
    bf16x4 pb;
#pragma unroll
    for (int r = 0; r < 4; ++r) pb[r] = (short)f2bf(p[r]);
    int c8 = key >> 3;                     // 16B chunk index in row
    int addr = lr * 4096 + ((c8 ^ (lr & 7)) << 4) + ((key & 7) << 1);
    *(bf16x4*)((char*)P + addr) = pb;
  }
  __syncthreads();

  // PV: ctx[q][d] = sum_k P[q][k] * V[k][d];  V^T rows from global (L2-hot)
  const unsigned short* Bv = vT + (size_t)(hz >> 2) * 524288 + bz * 2048;
  const int d0 = w * 16;
  f32x4 cfr = {};
  for (int kt = 0; kt < 64; ++kt) {
    int c8 = kt * 4 + kq;
    bf16x8 pfr =
        *(const bf16x8*)((const char*)P + lr * 4096 + ((c8 ^ (lr & 7)) << 4));
    bf16x8 vfr = *(const bf16x8*)(Bv + (size_t)(d0 + lr) * 4096 +
                                  kt * 32 + kq * 8);
    cfr = __builtin_amdgcn_mfma_f32_16x16x32_bf16(pfr, vfr, cfr, 0, 0, 0);
  }
#pragma unroll
  for (int r = 0; r < 4; ++r) {
    int q = kq * 4 + r;
    ctx[((size_t)(bz * 2048 + q0 + q) * 2048) + hz * 128 + d0 + lr] =
        f2bf(cfr[r]);
  }
}

// ===========================================================================
// 256x128 8-wave double-buffered GEMM, BK=64 (front-loaded gll16 + swizzle)
// ===========================================================================
template <bool OUT_BF16>
__global__ __launch_bounds__(512, 2) void gemm256(
    const unsigned short* __restrict__ A, const unsigned short* __restrict__ Bt,
    void* __restrict__ C_, int K, int lda, int ldb, int ldc) {
  __shared__ unsigned short As[2][256 * 64];  // 64 KB
  __shared__ unsigned short Bs[2][128 * 64];  // 32 KB
  const int tid = threadIdx.x;
  const int bm0 = blockIdx.y * 256, bn0 = blockIdx.x * 128;
  const int lane = tid & 63, wid = tid >> 6;
  const int wr = wid >> 2, wc = wid & 3;
  const int lr = lane & 15, kq = lane >> 4;

  f32x4 acc[8][2] = {};

  int sArow[4], sAcc[4], sBrow[2], sBcc[2];
#pragma unroll
  for (int R = 0; R < 4; ++R) {
    int c = R * 512 + tid;
    sArow[R] = c >> 3;
    sAcc[R]  = (c & 7) ^ (sArow[R] & 7);
  }
#pragma unroll
  for (int R = 0; R < 2; ++R) {
    int c = R * 512 + tid;
    sBrow[R] = c >> 3;
    sBcc[R]  = (c & 7) ^ (sBrow[R] & 7);
  }

  auto stage = [&](int buf, int k0) {
#pragma unroll
    for (int R = 0; R < 4; ++R)
      ASYNC16(&As[buf][(R * 512 + tid) * 8],
              A + (size_t)(bm0 + sArow[R]) * lda + k0 + sAcc[R] * 8);
#pragma unroll
    for (int R = 0; R < 2; ++R)
      ASYNC16(&Bs[buf][(R * 512 + tid) * 8],
              Bt + (size_t)(bn0 + sBrow[R]) * ldb + k0 + sBcc[R] * 8);
  };

  const int NT = K >> 6;
  stage(0, 0);
  __syncthreads();
  int cur = 0;
  for (int t = 0; t < NT; ++t) {
    if (t + 1 < NT) stage(cur ^ 1, (t + 1) << 6);
    const unsigned short* Ac = As[cur];
    const unsigned short* Bc = Bs[cur];
    __builtin_amdgcn_s_setprio(1);
#pragma unroll
    for (int ks = 0; ks < 2; ++ks) {
      bf16x8 afr[8];
#pragma unroll
      for (int i = 0; i < 8; ++i) {
        int row = wr * 128 + i * 16 + lr;
        int cch = (ks * 4 + kq) ^ (row & 7);
        afr[i] = *(const bf16x8*)&Ac[(row * 8 + cch) * 8];
      }
#pragma unroll
      for (int j = 0; j < 2; ++j) {
        int brow = wc * 32 + j * 16 + lr;
        int cch = (ks * 4 + kq) ^ (brow & 7);
        bf16x8 bfr = *(const bf16x8*)&Bc[(brow * 8 + cch) * 8];
#pragma unroll
        for (int i = 0; i < 8; ++i)
          acc[i][j] = __builtin_amdgcn_mfma_f32_16x16x32_bf16(afr[i], bfr,
                                                              acc[i][j], 0, 0, 0);
      }
    }
    __builtin_amdgcn_s_setprio(0);
    __syncthreads();
    cur ^= 1;
  }

#pragma unroll
  for (int i = 0; i < 8; ++i)
#pragma unroll
    for (int j = 0; j < 2; ++j) {
      int rowb = bm0 + wr * 128 + i * 16 + kq * 4;
      int col = bn0 + wc * 32 + j * 16 + lr;
#pragma unroll
      for (int r = 0; r < 4; ++r) {
        if constexpr (OUT_BF16)
          ((unsigned short*)C_)[(size_t)(rowb + r) * ldc + col] = f2bf(acc[i][j][r]);
        else
          ((float*)C_)[(size_t)(rowb + r) * ldc + col] = acc[i][j][r];
      }
    }
}

// ---- same structure, dual-B GeGLU: h = (A@B1^T) * gelu(A@B2^T) -------------
__global__ __launch_bounds__(512, 2) void gemm_geglu256(
    const unsigned short* __restrict__ A, const unsigned short* __restrict__ B1,
    const unsigned short* __restrict__ B2, unsigned short* __restrict__ H_,
    int K, int lda, int ldb, int ldc) {
  __shared__ unsigned short As[2][256 * 64];   // 64 KB
  __shared__ unsigned short B1s[2][128 * 64];  // 32 KB
  __shared__ unsigned short B2s[2][128 * 64];  // 32 KB
  const int tid = threadIdx.x;
  const int bm0 = blockIdx.y * 256, bn0 = blockIdx.x * 128;
  const int lane = tid & 63, wid = tid >> 6;
  const int wr = wid >> 2, wc = wid & 3;
  const int lr = lane & 15, kq = lane >> 4;

  f32x4 accu[8][2] = {};
  f32x4 accg[8][2] = {};

  int sArow[4], sAcc[4], sBrow[2], sBcc[2];
#pragma unroll
  for (int R = 0; R < 4; ++R) {
    int c = R * 512 + tid;
    sArow[R] = c >> 3;
    sAcc[R]  = (c & 7) ^ (sArow[R] & 7);
  }
#pragma unroll
  for (int R = 0; R < 2; ++R) {
    int c = R * 512 + tid;
    sBrow[R] = c >> 3;
    sBcc[R]  = (c & 7) ^ (sBrow[R] & 7);
  }

  auto stage = [&](int buf, int k0) {
#pragma unroll
    for (int R = 0; R < 4; ++R)
      ASYNC16(&As[buf][(R * 512 + tid) * 8],
              A + (size_t)(bm0 + sArow[R]) * lda + k0 + sAcc[R] * 8);
#pragma unroll
    for (int R = 0; R < 2; ++R)
      ASYNC16(&B1s[buf][(R * 512 + tid) * 8],
              B1 + (size_t)(bn0 + sBrow[R]) * ldb + k0 + sBcc[R] * 8);
#pragma unroll
    for (int R = 0; R < 2; ++R)
      ASYNC16(&B2s[buf][(R * 512 + tid) * 8],
              B2 + (size_t)(bn0 + sBrow[R]) * ldb + k0 + sBcc[R] * 8);
  };

  const int NT = K >> 6;
  stage(0, 0);
  __syncthreads();
  int cur = 0;
  for (int t = 0; t < NT; ++t) {
    if (t + 1 < NT) stage(cur ^ 1, (t + 1) << 6);
    const unsigned short* Ac = As[cur];
    const unsigned short* B1c = B1s[cur];
    const unsigned short* B2c = B2s[cur];
    __builtin_amdgcn_s_setprio(1);
#pragma unroll
    for (int ks = 0; ks < 2; ++ks) {
      bf16x8 afr[8];
#pragma unroll
      for (int i = 0; i < 8; ++i) {
        int row = wr * 128 + i * 16 + lr;
        int cch = (ks * 4 + kq) ^ (row & 7);
        afr[i] = *(const bf16x8*)&Ac[(row * 8 + cch) * 8];
      }
#pragma unroll
      for (int j = 0; j < 2; ++j) {
        int brow = wc * 32 + j * 16 + lr;
        int cch = (ks * 4 + kq) ^ (brow & 7);
        bf16x8 b1 = *(const bf16x8*)&B1c[(brow * 8 + cch) * 8];
        bf16x8 b2 = *(const bf16x8*)&B2c[(brow * 8 + cch) * 8];
#pragma unroll
        for (int i = 0; i < 8; ++i) {
          accu[i][j] = __builtin_amdgcn_mfma_f32_16x16x32_bf16(afr[i], b1,
                                                               accu[i][j], 0, 0, 0);
          accg[i][j] = __builtin_amdgcn_mfma_f32_16x16x32_bf16(afr[i], b2,
                                                               accg[i][j], 0, 0, 0);
        }
      }
    }
    __builtin_amdgcn_s_setprio(0);
    __syncthreads();
    cur ^= 1;
  }

#pragma unroll
  for (int i = 0; i < 8; ++i)
#pragma unroll
    for (int j = 0; j < 2; ++j) {
      int rowb = bm0 + wr * 128 + i * 16 + kq * 4;
      int col = bn0 + wc * 32 + j * 16 + lr;
#pragma unroll
      for (int r = 0; r < 4; ++r) {
        float u = accu[i][j][r];
        float g = accg[i][j][r];
        float tv = tanhf(0.7978845608028654f * (g + 0.044715f * g * g * g));
        float hv = u * 0.5f * g * (1.0f + tv);
        H_[(size_t)(rowb + r) * ldc + col] = f2bf(hv);
      }
    }
}

// ---------------------------------------------------------------------------
extern "C" void kernel_launch(void* const* d_in, const int* in_sizes, int n_in,
                              void* d_out, int out_size, void* d_ws, size_t ws_size,
                              hipStream_t stream) {
  const float* x   = (const float*)d_in[0];
  const float* wq  = (const float*)d_in[1];
  const float* wk  = (const float*)d_in[2];
  const float* wv  = (const float*)d_in[3];
  const float* wo  = (const float*)d_in[4];
  const float* w1  = (const float*)d_in[5];
  const float* w2  = (const float*)d_in[6];
  const float* n1w = (const float*)d_in[7];
  const float* n2w = (const float*)d_in[8];

  float* out    = (float*)d_out;
  float* x2_out = out;
  float* k_out  = out + 8388608;
  float* v_out  = out + 16777216;
  float* attn   = out + 25165824;  // 134,217,728 f32

  char* ws = (char*)d_ws;
  unsigned short* wqT  = (unsigned short*)(ws + 0);
  unsigned short* wkT  = (unsigned short*)(ws + 8388608);
  unsigned short* wvT  = (unsigned short*)(ws + 10485760);
  unsigned short* woT  = (unsigned short*)(ws + 12582912);
  unsigned short* w1T  = (unsigned short*)(ws + 20971520);
  unsigned short* w2T  = (unsigned short*)(ws + 88080384);
  unsigned short* qh   = (unsigned short*)(ws + 121634816);
  unsigned short* kh   = (unsigned short*)(ws + 138412032);
  unsigned short* vhT  = (unsigned short*)(ws + 142606336);
  unsigned short* ctx  = (unsigned short*)(ws + 146800640);
  float*          ao   = (float*)(ws + 163577856);
  unsigned short* hbuf = (unsigned short*)(ws + 121634816);  // alias qh..ao (dead)
  unsigned short* x1b  = (unsigned short*)(ws + 197132288);
  unsigned short* fc   = (unsigned short*)(ws + 213909504);
  // ws total: 230,686,720 bytes

  // bf16 scratch inside not-yet-written attn region of d_out
  unsigned short* xb = (unsigned short*)attn;   // bf16(x), 8,388,608 elems
  unsigned short* xq = xb + 8388608;            // bf16(rope(x))

  dim3 blk(256);
  dim3 blk512(512);

  // 1) weight convert+transpose (f32 [K,N] -> bf16 [N,K])
  kconvT<<<dim3(64, 64), blk, 0, stream>>>(wq, wqT, 2048, 2048);
  kconvT<<<dim3(16, 64), blk, 0, stream>>>(wk, wkT, 2048, 512);
  kconvT<<<dim3(16, 64), blk, 0, stream>>>(wv, wvT, 2048, 512);
  kconvT<<<dim3(64, 64), blk, 0, stream>>>(wo, woT, 2048, 2048);
  kconvT<<<dim3(512, 64), blk, 0, stream>>>(w1, w1T, 2048, 16384);
  kconvT<<<dim3(64, 256), blk, 0, stream>>>(w2, w2T, 8192, 2048);

  // 2) v_flat = x ; xb = bf16(x)
  kcopy<<<8192, blk, 0, stream>>>((const f32x4*)x, (f32x4*)v_out, (u16x4*)xb);
  // 3) k_flat = rope(x) f32 ; xq = bf16(rope(x))
  krope<<<16384, blk, 0, stream>>>(x, k_out, xq);

  // 4) projections
  gemm256<true><<<dim3(16, 16), blk512, 0, stream>>>(
      xq, wqT, qh, 2048, 2048, 2048, 2048);
  gemm_bt<true, false><<<dim3(4, 32), blk, 0, stream>>>(
      xq, wkT, kh, 2048, 2048, 2048, 512, 1.0f);
  gemm_bt<true, true><<<dim3(4, 32), blk, 0, stream>>>(
      xb, wvT, vhT, 2048, 2048, 2048, 4096, 1.0f);

  // 5) fused scores + softmax + attn write + PV -> ctx
  kattn<<<dim3(128, 32), blk512, 0, stream>>>(qh, kh, vhT, attn, ctx);

  // 6) attn_out = ctx @ wo (f32)
  gemm256<false><<<dim3(16, 16), blk512, 0, stream>>>(
      ctx, woT, (void*)ao, 2048, 2048, 2048, 2048);
  // 7) x1b = rmsnorm(x + ao) * n1w
  krms1<<<4096, blk, 0, stream>>>(x, ao, n1w, x1b);
  // 8) h = u * gelu(gate)  (fused dual GEMM, uv never materialized)
  gemm_geglu256<<<dim3(64, 16), blk512, 0, stream>>>(
      x1b, w1T, w1T + 16777216, hbuf, 2048, 2048, 2048, 8192);
  // 9) fc = h @ w2
  gemm256<true><<<dim3(16, 16), blk512, 0, stream>>>(
      hbuf, w2T, fc, 8192, 8192, 8192, 2048);
  // 10) x2 = rmsnorm(x1 + fc) * n2w
  krms2<<<4096, blk, 0, stream>>>(x1b, fc, n2w, x2_out);
}

// Round 7
// 1246.487 us; speedup vs baseline: 1.1087x; 1.1087x over previous
//
#include <hip/hip_runtime.h>
#include <hip/hip_bf16.h>

// ---------------------------------------------------------------------------
// TransformerBlock: B=2 N=2048 E=2048 H=16 G=4 D=128 HID=8192
// out = [ x2 (8.39M f32) | k_flat (8.39M) | v_flat (8.39M) | attn (134.2M) ]
// R7: kattn v3 — async LDS staging. R6 diagnosis: ~50cy stall/instr, all pipes
//     idle -> serial load->MFMA chains at L3 latency (K/V 8MB > 4MB L2/XCD,
//     VGPR=56 so few loads in flight). Fix: global_load_lds dbuf staging for
//     K (128-key tiles) and V (32-key tiles), pre-swizzled src + swizzled
//     reads; P reuses K LDS after scores; 80KB total -> still 2 blocks/CU.
// ---------------------------------------------------------------------------

using f32x4  = __attribute__((ext_vector_type(4))) float;
using bf16x8 = __attribute__((ext_vector_type(8))) short;
using bf16x4 = __attribute__((ext_vector_type(4))) short;
using u16x4  = __attribute__((ext_vector_type(4))) unsigned short;

#define DEV __device__ __forceinline__

// async global->LDS, 16B per lane; LDS dest must be wave-uniform base + lane*16
#define ASYNC16(lds, g)                                                        \
  __builtin_amdgcn_global_load_lds(                                           \
      (const __attribute__((address_space(1))) void*)(g),                      \
      (__attribute__((address_space(3))) void*)(lds), 16, 0, 0)

DEV unsigned short f2bf(float f) {
  unsigned int u = __float_as_uint(f);
  return (unsigned short)((u + 0x7fffu + ((u >> 16) & 1u)) >> 16);
}
DEV float bf2f(unsigned short h) {
  return __uint_as_float(((unsigned int)h) << 16);
}

DEV float waveRedSum(float v) {
#pragma unroll
  for (int o = 32; o; o >>= 1) v += __shfl_xor(v, o);
  return v;
}

// ---- transpose+convert: in f32 [K,N] -> out bf16 [N,K] ---------------------
__global__ __launch_bounds__(256) void kconvT(const float* __restrict__ in,
                                              unsigned short* __restrict__ out,
                                              int K, int N) {
  __shared__ float tile[32][33];
  int bx = blockIdx.x * 32;  // N dim
  int by = blockIdx.y * 32;  // K dim
  int tx = threadIdx.x & 31;
  int ty = threadIdx.x >> 5;  // 0..7
#pragma unroll
  for (int i = 0; i < 32; i += 8)
    tile[ty + i][tx] = in[(size_t)(by + ty + i) * N + bx + tx];
  __syncthreads();
#pragma unroll
  for (int i = 0; i < 32; i += 8)
    out[(size_t)(bx + ty + i) * K + by + tx] = f2bf(tile[tx][ty + i]);
}

// ---- v_flat = x (f32 copy) and x_bf16 --------------------------------------
__global__ __launch_bounds__(256) void kcopy(const f32x4* __restrict__ x,
                                             f32x4* __restrict__ v,
                                             u16x4* __restrict__ xb) {
  int i = blockIdx.x * 256 + threadIdx.x;  // exactly 2,097,152 threads
  f32x4 val = x[i];
  v[i] = val;
  u16x4 o;
  o[0] = f2bf(val[0]); o[1] = f2bf(val[1]); o[2] = f2bf(val[2]); o[3] = f2bf(val[3]);
  xb[i] = o;
}

// ---- RoPE on per-head slices of x -> k_flat f32 (d_out) + xq bf16 ----------
__global__ __launch_bounds__(256) void krope(const float* __restrict__ x,
                                             float* __restrict__ kout,
                                             unsigned short* __restrict__ xq) {
  int idx = blockIdx.x * 256 + threadIdx.x;  // B*N*H*64 = 4,194,304
  int f  = idx & 63;
  int h  = (idx >> 6) & 15;
  int bn = idx >> 10;          // b*2048+n
  int n  = bn & 2047;
  size_t base = (size_t)bn * 2048 + h * 128;
  float inv = exp2f((float)f * (-13.287712379549449f / 64.0f));
  float ang = (float)n * inv;
  float c = cosf(ang), s = sinf(ang);
  float a = x[base + f], b = x[base + f + 64];
  float k1 = a * c - b * s;
  float k2 = b * c + a * s;
  kout[base + f]      = k1;
  kout[base + f + 64] = k2;
  xq[base + f]      = f2bf(k1);
  xq[base + f + 64] = f2bf(k2);
}

// ---- x1b = bf16(rmsnorm(x + ao) * w) ---------------------------------------
__global__ __launch_bounds__(256) void krms1(const float* __restrict__ x,
                                             const float* __restrict__ ao,
                                             const float* __restrict__ w,
                                             unsigned short* __restrict__ x1b) {
  size_t row = blockIdx.x;
  const f32x4* xp = (const f32x4*)(x + row * 2048);
  const f32x4* ap = (const f32x4*)(ao + row * 2048);
  int tid = threadIdx.x;
  f32x4 t0 = xp[tid * 2] + ap[tid * 2];
  f32x4 t1 = xp[tid * 2 + 1] + ap[tid * 2 + 1];
  float ss = 0.f;
#pragma unroll
  for (int i = 0; i < 4; ++i) ss += t0[i] * t0[i] + t1[i] * t1[i];
  ss = waveRedSum(ss);
  __shared__ float red[4];
  int wid = tid >> 6, lane = tid & 63;
  if (!lane) red[wid] = ss;
  __syncthreads();
  ss = red[0] + red[1] + red[2] + red[3];
  float rr = rsqrtf(ss * (1.0f / 2048.0f) + 1e-6f);
  const f32x4* wp = (const f32x4*)w;
  f32x4 w0 = wp[tid * 2], w1 = wp[tid * 2 + 1];
  u16x4 o0, o1;
#pragma unroll
  for (int i = 0; i < 4; ++i) {
    o0[i] = f2bf(t0[i] * rr * w0[i]);
    o1[i] = f2bf(t1[i] * rr * w1[i]);
  }
  u16x4* op = (u16x4*)(x1b + row * 2048);
  op[tid * 2] = o0;
  op[tid * 2 + 1] = o1;
}

// ---- x2 = f32(rmsnorm(x1b + fc) * w) -> d_out ------------------------------
__global__ __launch_bounds__(256) void krms2(const unsigned short* __restrict__ x1b,
                                             const unsigned short* __restrict__ fc,
                                             const float* __restrict__ w,
                                             float* __restrict__ out) {
  size_t row = blockIdx.x;
  const u16x4* xp = (const u16x4*)(x1b + row * 2048);
  const u16x4* fp = (const u16x4*)(fc + row * 2048);
  int tid = threadIdx.x;
  u16x4 a0 = xp[tid * 2], a1 = xp[tid * 2 + 1];
  u16x4 b0 = fp[tid * 2], b1 = fp[tid * 2 + 1];
  f32x4 t0, t1;
#pragma unroll
  for (int i = 0; i < 4; ++i) {
    t0[i] = bf2f(a0[i]) + bf2f(b0[i]);
    t1[i] = bf2f(a1[i]) + bf2f(b1[i]);
  }
  float ss = 0.f;
#pragma unroll
  for (int i = 0; i < 4; ++i) ss += t0[i] * t0[i] + t1[i] * t1[i];
  ss = waveRedSum(ss);
  __shared__ float red[4];
  int wid = tid >> 6, lane = tid & 63;
  if (!lane) red[wid] = ss;
  __syncthreads();
  ss = red[0] + red[1] + red[2] + red[3];
  float rr = rsqrtf(ss * (1.0f / 2048.0f) + 1e-6f);
  const f32x4* wp = (const f32x4*)w;
  f32x4 w0 = wp[tid * 2], w1 = wp[tid * 2 + 1];
  f32x4* op = (f32x4*)(out + row * 2048);
  op[tid * 2]     = t0 * rr * w0;
  op[tid * 2 + 1] = t1 * rr * w1;
}

// ---- 128x128 MFMA GEMM (small shapes: k/v projections) ---------------------
template <bool OUT_BF16, bool TRANS_OUT>
__global__ __launch_bounds__(256, 2) void gemm_bt(
    const unsigned short* __restrict__ A, const unsigned short* __restrict__ Bt,
    void* __restrict__ C_, int K, int lda, int ldb, int ldc, float alpha) {
  __shared__ unsigned short As[128 * 32];
  __shared__ unsigned short Bs[128 * 32];
  const int tid = threadIdx.x;
  const int bm0 = blockIdx.y * 128, bn0 = blockIdx.x * 128;

  f32x4 acc[4][4] = {};

  const int lane = tid & 63, wid = tid >> 6;
  const int wr = wid >> 1, wc = wid & 1;
  const int lr = lane & 15, kq = lane >> 4;
  const int srow = tid >> 2;        // 0..63
  const int scol = (tid & 3) * 8;   // 0,8,16,24
  unsigned short* AsW = As + tid * 8;
  unsigned short* BsW = Bs + tid * 8;

  for (int kt = 0; kt < K; kt += 32) {
    ASYNC16(AsW,        A + (size_t)(bm0 + srow)      * lda + kt + scol);
    ASYNC16(AsW + 2048, A + (size_t)(bm0 + srow + 64) * lda + kt + scol);
    ASYNC16(BsW,        Bt + (size_t)(bn0 + srow)      * ldb + kt + scol);
    ASYNC16(BsW + 2048, Bt + (size_t)(bn0 + srow + 64) * ldb + kt + scol);
    __syncthreads();
    bf16x8 afr[4], bfr[4];
#pragma unroll
    for (int i = 0; i < 4; ++i)
      afr[i] = *(const bf16x8*)&As[(wr * 64 + i * 16 + lr) * 32 + kq * 8];
#pragma unroll
    for (int j = 0; j < 4; ++j)
      bfr[j] = *(const bf16x8*)&Bs[(wc * 64 + j * 16 + lr) * 32 + kq * 8];
#pragma unroll
    for (int i = 0; i < 4; ++i)
#pragma unroll
      for (int j = 0; j < 4; ++j)
        acc[i][j] = __builtin_amdgcn_mfma_f32_16x16x32_bf16(afr[i], bfr[j],
                                                            acc[i][j], 0, 0, 0);
    __syncthreads();
  }

#pragma unroll
  for (int i = 0; i < 4; ++i)
#pragma unroll
    for (int j = 0; j < 4; ++j) {
      int rowb = bm0 + wr * 64 + i * 16 + kq * 4;
      int col = bn0 + wc * 64 + j * 16 + lr;
#pragma unroll
      for (int r = 0; r < 4; ++r) {
        float v = acc[i][j][r] * alpha;
        size_t idx = TRANS_OUT ? ((size_t)col * ldc + (rowb + r))
                               : ((size_t)(rowb + r) * ldc + col);
        if constexpr (OUT_BF16)
          ((unsigned short*)C_)[idx] = f2bf(v);
        else
          ((float*)C_)[idx] = v;
      }
    }
}

// ===========================================================================
// Fused attention v3: async-staged. 8 waves (512 thr), 16 q-rows per block.
// LDS (80KB = 2 blocks/CU):
//   U[64KB]   : scores phase = K-tile dbuf (2 x 128keys x 128d, swizzled)
//               PV phase     = P [16 q][2048 keys] bf16 (swizzled chunks)
//   Vbuf[16KB]: softmax phase = redm/reds ; PV = V-tile dbuf (2 x 128d x 32k)
// All global->LDS via global_load_lds (deep async queue, VGPR-free) with
// pre-swizzled SOURCE + swizzled READ (same involution both sides):
//   K: chunk c in row ^= (row&7)   V: chunk c in d-row ^= (d&3)
// ===========================================================================
__global__ __launch_bounds__(512, 4) void kattn(
    const unsigned short* __restrict__ qh,   // [b][n][h*128+d] ld 2048
    const unsigned short* __restrict__ kh,   // [b][n][g*128+d] ld 512
    const unsigned short* __restrict__ vT,   // [g*128+d][b*2048+key] ld 4096
    float* __restrict__ attn,                // [b][h][q][key]
    unsigned short* __restrict__ ctx) {      // [b][n][h*128+d] ld 2048
  __shared__ __align__(16) char LDSBUF[81920];
  char* U = LDSBUF;                 // 64KB: K dbuf, then P
  char* Vb = LDSBUF + 65536;        // 16KB: red arrays, then V dbuf
  float* redm = (float*)Vb;         // [8][16]
  float* reds = redm + 128;         // [8][16]

  const int tid = threadIdx.x;
  const int lane = tid & 63, w = tid >> 6;   // w 0..7
  const int lr = lane & 15, kq = lane >> 4;  // q = lr, quarter = kq
  const int z = blockIdx.y, bz = z >> 4, hz = z & 15;
  const int q0 = blockIdx.x * 16;

  // Q fragments (B-operand): Q[q=lr][k], k-contiguous
  const unsigned short* Aq =
      qh + ((size_t)(bz * 2048 + q0 + lr) * 2048 + hz * 128);
  bf16x8 qfr[4];
#pragma unroll
  for (int kk = 0; kk < 4; ++kk)
    qfr[kk] = *(const bf16x8*)(Aq + kk * 32 + kq * 8);

  // --- scores: C[key][q] = sum_d K[key][d] * Q[q][d], K staged in LDS ------
  const unsigned short* Kb =
      kh + ((size_t)(bz * 2048) * 512 + (hz >> 2) * 128);
  // staging descriptors: 4 slots/thread, slot = R*512+tid -> (row, chunk)
  const int srow = [&] { return 0; }();  // (silence unused warnings pattern)
  int kr[4], kc[4];
#pragma unroll
  for (int R = 0; R < 4; ++R) {
    int slot = R * 512 + tid;
    kr[R] = slot >> 4;                  // key row 0..127
    kc[R] = (slot & 15) ^ (kr[R] & 7);  // pre-swizzled source chunk
  }
  auto stageK = [&](int buf, int t) {
#pragma unroll
    for (int R = 0; R < 4; ++R)
      ASYNC16(U + buf * 32768 + (R * 512 + tid) * 16,
              Kb + (size_t)(t * 128 + kr[R]) * 512 + kc[R] * 8);
  };

  f32x4 acc[16];
#pragma unroll
  for (int t = 0; t < 16; ++t) acc[t] = f32x4{0.f, 0.f, 0.f, 0.f};

  stageK(0, 0);
  __syncthreads();
  int cur = 0;
#pragma unroll
  for (int t = 0; t < 16; ++t) {
    if (t < 15) stageK(cur ^ 1, t + 1);
    // wave w computes its 16-key j-tile: rows w*16..+16 of this 128-key tile
#pragma unroll
    for (int kk = 0; kk < 4; ++kk) {
      int row = w * 16 + lr;
      int cch = (kk * 4 + kq) ^ (row & 7);
      bf16x8 kfr = *(const bf16x8*)(U + cur * 32768 + row * 256 + cch * 16);
      acc[t] = __builtin_amdgcn_mfma_f32_16x16x32_bf16(kfr, qfr[kk], acc[t],
                                                       0, 0, 0);
    }
    __syncthreads();
    cur ^= 1;
  }

  // --- softmax (per-lane q-row = lr) ---------------------------------------
  const float scale = 0.08838834764831845f;
  float mx = -3.4e38f;
#pragma unroll
  for (int t = 0; t < 16; ++t) {
    acc[t] *= scale;
#pragma unroll
    for (int r = 0; r < 4; ++r) mx = fmaxf(mx, acc[t][r]);
  }
  mx = fmaxf(mx, __shfl_xor(mx, 16));
  mx = fmaxf(mx, __shfl_xor(mx, 32));
  if (kq == 0) redm[w * 16 + lr] = mx;
  __syncthreads();
  mx = redm[lr];
#pragma unroll
  for (int ww = 1; ww < 8; ++ww) mx = fmaxf(mx, redm[ww * 16 + lr]);

  float sm = 0.f;
#pragma unroll
  for (int t = 0; t < 16; ++t) {
#pragma unroll
    for (int r = 0; r < 4; ++r) {
      float e = __expf(acc[t][r] - mx);
      acc[t][r] = e;
      sm += e;
    }
  }
  sm += __shfl_xor(sm, 16);
  sm += __shfl_xor(sm, 32);
  if (kq == 0) reds[w * 16 + lr] = sm;
  __syncthreads();
  float smt = reds[lr];
#pragma unroll
  for (int ww = 1; ww < 8; ++ww) smt += reds[ww * 16 + lr];
  float inv = 1.0f / smt;

  // --- write attn f32 + P bf16 into U (K staging done; swizzled chunks) ----
  float* arow = attn + (((size_t)z * 2048 + q0 + lr) * 2048);
#pragma unroll
  for (int t = 0; t < 16; ++t) {
    int key = t * 128 + w * 16 + kq * 4;
    f32x4 p = acc[t] * inv;
    *(f32x4*)(arow + key) = p;
    bf16x4 pb;
#pragma unroll
    for (int r = 0; r < 4; ++r) pb[r] = (short)f2bf(p[r]);
    int c8 = key >> 3;  // 16B chunk index in q-row
    *(bf16x4*)(U + lr * 4096 + ((c8 ^ (lr & 7)) << 4) + ((key & 7) << 1)) = pb;
  }
  __syncthreads();  // P ready; all red reads done -> Vb reusable

  // --- PV: ctx[q][d] = sum_k P[q][k] V[k][d]; V staged (32-key tiles) ------
  const unsigned short* Bv = vT + (size_t)(hz >> 2) * 524288 + bz * 2048;
  // staging: 1 slot/thread: slot=tid -> (d=slot>>2, c=slot&3), src pre-swz
  const int vd = tid >> 2;
  const int vc = (tid & 3) ^ (vd & 3);
  auto stageV = [&](int buf, int t) {
    ASYNC16(Vb + buf * 8192 + tid * 16,
            Bv + (size_t)vd * 4096 + t * 32 + vc * 8);
  };

  const int d0 = w * 16;
  f32x4 cfr = {};
  stageV(0, 0);
  __syncthreads();
  cur = 0;
  for (int t = 0; t < 64; ++t) {
    if (t < 63) stageV(cur ^ 1, t + 1);
    int c8 = t * 4 + kq;
    bf16x8 pfr = *(const bf16x8*)(U + lr * 4096 + ((c8 ^ (lr & 7)) << 4));
    int dd = d0 + lr;
    bf16x8 vfr = *(const bf16x8*)(Vb + cur * 8192 + dd * 64 +
                                  ((kq ^ (dd & 3)) << 4));
    cfr = __builtin_amdgcn_mfma_f32_16x16x32_bf16(pfr, vfr, cfr, 0, 0, 0);
    __syncthreads();
    cur ^= 1;
  }
#pragma unroll
  for (int r = 0; r < 4; ++r) {
    int q = kq * 4 + r;
    ctx[((size_t)(bz * 2048 + q0 + q) * 2048) + hz * 128 + d0 + lr] =
        f2bf(cfr[r]);
  }
}

// ===========================================================================
// 256x128 8-wave double-buffered GEMM, BK=64 (front-loaded gll16 + swizzle)
// ===========================================================================
template <bool OUT_BF16>
__global__ __launch_bounds__(512, 2) void gemm256(
    const unsigned short* __restrict__ A, const unsigned short* __restrict__ Bt,
    void* __restrict__ C_, int K, int lda, int ldb, int ldc) {
  __shared__ unsigned short As[2][256 * 64];  // 64 KB
  __shared__ unsigned short Bs[2][128 * 64];  // 32 KB
  const int tid = threadIdx.x;
  const int bm0 = blockIdx.y * 256, bn0 = blockIdx.x * 128;
  const int lane = tid & 63, wid = tid >> 6;
  const int wr = wid >> 2, wc = wid & 3;
  const int lr = lane & 15, kq = lane >> 4;

  f32x4 acc[8][2] = {};

  int sArow[4], sAcc[4], sBrow[2], sBcc[2];
#pragma unroll
  for (int R = 0; R < 4; ++R) {
    int c = R * 512 + tid;
    sArow[R] = c >> 3;
    sAcc[R]  = (c & 7) ^ (sArow[R] & 7);
  }
#pragma unroll
  for (int R = 0; R < 2; ++R) {
    int c = R * 512 + tid;
    sBrow[R] = c >> 3;
    sBcc[R]  = (c & 7) ^ (sBrow[R] & 7);
  }

  auto stage = [&](int buf, int k0) {
#pragma unroll
    for (int R = 0; R < 4; ++R)
      ASYNC16(&As[buf][(R * 512 + tid) * 8],
              A + (size_t)(bm0 + sArow[R]) * lda + k0 + sAcc[R] * 8);
#pragma unroll
    for (int R = 0; R < 2; ++R)
      ASYNC16(&Bs[buf][(R * 512 + tid) * 8],
              Bt + (size_t)(bn0 + sBrow[R]) * ldb + k0 + sBcc[R] * 8);
  };

  const int NT = K >> 6;
  stage(0, 0);
  __syncthreads();
  int cur = 0;
  for (int t = 0; t < NT; ++t) {
    if (t + 1 < NT) stage(cur ^ 1, (t + 1) << 6);
    const unsigned short* Ac = As[cur];
    const unsigned short* Bc = Bs[cur];
    __builtin_amdgcn_s_setprio(1);
#pragma unroll
    for (int ks = 0; ks < 2; ++ks) {
      bf16x8 afr[8];
#pragma unroll
      for (int i = 0; i < 8; ++i) {
        int row = wr * 128 + i * 16 + lr;
        int cch = (ks * 4 + kq) ^ (row & 7);
        afr[i] = *(const bf16x8*)&Ac[(row * 8 + cch) * 8];
      }
#pragma unroll
      for (int j = 0; j < 2; ++j) {
        int brow = wc * 32 + j * 16 + lr;
        int cch = (ks * 4 + kq) ^ (brow & 7);
        bf16x8 bfr = *(const bf16x8*)&Bc[(brow * 8 + cch) * 8];
#pragma unroll
        for (int i = 0; i < 8; ++i)
          acc[i][j] = __builtin_amdgcn_mfma_f32_16x16x32_bf16(afr[i], bfr,
                                                              acc[i][j], 0, 0, 0);
      }
    }
    __builtin_amdgcn_s_setprio(0);
    __syncthreads();
    cur ^= 1;
  }

#pragma unroll
  for (int i = 0; i < 8; ++i)
#pragma unroll
    for (int j = 0; j < 2; ++j) {
      int rowb = bm0 + wr * 128 + i * 16 + kq * 4;
      int col = bn0 + wc * 32 + j * 16 + lr;
#pragma unroll
      for (int r = 0; r < 4; ++r) {
        if constexpr (OUT_BF16)
          ((unsigned short*)C_)[(size_t)(rowb + r) * ldc + col] = f2bf(acc[i][j][r]);
        else
          ((float*)C_)[(size_t)(rowb + r) * ldc + col] = acc[i][j][r];
      }
    }
}

// ---- same structure, dual-B GeGLU: h = (A@B1^T) * gelu(A@B2^T) -------------
__global__ __launch_bounds__(512, 2) void gemm_geglu256(
    const unsigned short* __restrict__ A, const unsigned short* __restrict__ B1,
    const unsigned short* __restrict__ B2, unsigned short* __restrict__ H_,
    int K, int lda, int ldb, int ldc) {
  __shared__ unsigned short As[2][256 * 64];   // 64 KB
  __shared__ unsigned short B1s[2][128 * 64];  // 32 KB
  __shared__ unsigned short B2s[2][128 * 64];  // 32 KB
  const int tid = threadIdx.x;
  const int bm0 = blockIdx.y * 256, bn0 = blockIdx.x * 128;
  const int lane = tid & 63, wid = tid >> 6;
  const int wr = wid >> 2, wc = wid & 3;
  const int lr = lane & 15, kq = lane >> 4;

  f32x4 accu[8][2] = {};
  f32x4 accg[8][2] = {};

  int sArow[4], sAcc[4], sBrow[2], sBcc[2];
#pragma unroll
  for (int R = 0; R < 4; ++R) {
    int c = R * 512 + tid;
    sArow[R] = c >> 3;
    sAcc[R]  = (c & 7) ^ (sArow[R] & 7);
  }
#pragma unroll
  for (int R = 0; R < 2; ++R) {
    int c = R * 512 + tid;
    sBrow[R] = c >> 3;
    sBcc[R]  = (c & 7) ^ (sBrow[R] & 7);
  }

  auto stage = [&](int buf, int k0) {
#pragma unroll
    for (int R = 0; R < 4; ++R)
      ASYNC16(&As[buf][(R * 512 + tid) * 8],
              A + (size_t)(bm0 + sArow[R]) * lda + k0 + sAcc[R] * 8);
#pragma unroll
    for (int R = 0; R < 2; ++R)
      ASYNC16(&B1s[buf][(R * 512 + tid) * 8],
              B1 + (size_t)(bn0 + sBrow[R]) * ldb + k0 + sBcc[R] * 8);
#pragma unroll
    for (int R = 0; R < 2; ++R)
      ASYNC16(&B2s[buf][(R * 512 + tid) * 8],
              B2 + (size_t)(bn0 + sBrow[R]) * ldb + k0 + sBcc[R] * 8);
  };

  const int NT = K >> 6;
  stage(0, 0);
  __syncthreads();
  int cur = 0;
  for (int t = 0; t < NT; ++t) {
    if (t + 1 < NT) stage(cur ^ 1, (t + 1) << 6);
    const unsigned short* Ac = As[cur];
    const unsigned short* B1c = B1s[cur];
    const unsigned short* B2c = B2s[cur];
    __builtin_amdgcn_s_setprio(1);
#pragma unroll
    for (int ks = 0; ks < 2; ++ks) {
      bf16x8 afr[8];
#pragma unroll
      for (int i = 0; i < 8; ++i) {
        int row = wr * 128 + i * 16 + lr;
        int cch = (ks * 4 + kq) ^ (row & 7);
        afr[i] = *(const bf16x8*)&Ac[(row * 8 + cch) * 8];
      }
#pragma unroll
      for (int j = 0; j < 2; ++j) {
        int brow = wc * 32 + j * 16 + lr;
        int cch = (ks * 4 + kq) ^ (brow & 7);
        bf16x8 b1 = *(const bf16x8*)&B1c[(brow * 8 + cch) * 8];
        bf16x8 b2 = *(const bf16x8*)&B2c[(brow * 8 + cch) * 8];
#pragma unroll
        for (int i = 0; i < 8; ++i) {
          accu[i][j] = __builtin_amdgcn_mfma_f32_16x16x32_bf16(afr[i], b1,
                                                               accu[i][j], 0, 0, 0);
          accg[i][j] = __builtin_amdgcn_mfma_f32_16x16x32_bf16(afr[i], b2,
                                                               accg[i][j], 0, 0, 0);
        }
      }
    }
    __builtin_amdgcn_s_setprio(0);
    __syncthreads();
    cur ^= 1;
  }

#pragma unroll
  for (int i = 0; i < 8; ++i)
#pragma unroll
    for (int j = 0; j < 2; ++j) {
      int rowb = bm0 + wr * 128 + i * 16 + kq * 4;
      int col = bn0 + wc * 32 + j * 16 + lr;
#pragma unroll
      for (int r = 0; r < 4; ++r) {
        float u = accu[i][j][r];
        float g = accg[i][j][r];
        float tv = tanhf(0.7978845608028654f * (g + 0.044715f * g * g * g));
        float hv = u * 0.5f * g * (1.0f + tv);
        H_[(size_t)(rowb + r) * ldc + col] = f2bf(hv);
      }
    }
}

// ---------------------------------------------------------------------------
extern "C" void kernel_launch(void* const* d_in, const int* in_sizes, int n_in,
                              void* d_out, int out_size, void* d_ws, size_t ws_size,
                              hipStream_t stream) {
  const float* x   = (const float*)d_in[0];
  const float* wq  = (const float*)d_in[1];
  const float* wk  = (const float*)d_in[2];
  const float* wv  = (const float*)d_in[3];
  const float* wo  = (const float*)d_in[4];
  const float* w1  = (const float*)d_in[5];
  const float* w2  = (const float*)d_in[6];
  const float* n1w = (const float*)d_in[7];
  const float* n2w = (const float*)d_in[8];

  float* out    = (float*)d_out;
  float* x2_out = out;
  float* k_out  = out + 8388608;
  float* v_out  = out + 16777216;
  float* attn   = out + 25165824;  // 134,217,728 f32

  char* ws = (char*)d_ws;
  unsigned short* wqT  = (unsigned short*)(ws + 0);
  unsigned short* wkT  = (unsigned short*)(ws + 8388608);
  unsigned short* wvT  = (unsigned short*)(ws + 10485760);
  unsigned short* woT  = (unsigned short*)(ws + 12582912);
  unsigned short* w1T  = (unsigned short*)(ws + 20971520);
  unsigned short* w2T  = (unsigned short*)(ws + 88080384);
  unsigned short* qh   = (unsigned short*)(ws + 121634816);
  unsigned short* kh   = (unsigned short*)(ws + 138412032);
  unsigned short* vhT  = (unsigned short*)(ws + 142606336);
  unsigned short* ctx  = (unsigned short*)(ws + 146800640);
  float*          ao   = (float*)(ws + 163577856);
  unsigned short* hbuf = (unsigned short*)(ws + 121634816);  // alias qh..ao (dead)
  unsigned short* x1b  = (unsigned short*)(ws + 197132288);
  unsigned short* fc   = (unsigned short*)(ws + 213909504);
  // ws total: 230,686,720 bytes

  // bf16 scratch inside not-yet-written attn region of d_out
  unsigned short* xb = (unsigned short*)attn;   // bf16(x), 8,388,608 elems
  unsigned short* xq = xb + 8388608;            // bf16(rope(x))

  dim3 blk(256);
  dim3 blk512(512);

  // 1) weight convert+transpose (f32 [K,N] -> bf16 [N,K])
  kconvT<<<dim3(64, 64), blk, 0, stream>>>(wq, wqT, 2048, 2048);
  kconvT<<<dim3(16, 64), blk, 0, stream>>>(wk, wkT, 2048, 512);
  kconvT<<<dim3(16, 64), blk, 0, stream>>>(wv, wvT, 2048, 512);
  kconvT<<<dim3(64, 64), blk, 0, stream>>>(wo, woT, 2048, 2048);
  kconvT<<<dim3(512, 64), blk, 0, stream>>>(w1, w1T, 2048, 16384);
  kconvT<<<dim3(64, 256), blk, 0, stream>>>(w2, w2T, 8192, 2048);

  // 2) v_flat = x ; xb = bf16(x)
  kcopy<<<8192, blk, 0, stream>>>((const f32x4*)x, (f32x4*)v_out, (u16x4*)xb);
  // 3) k_flat = rope(x) f32 ; xq = bf16(rope(x))
  krope<<<16384, blk, 0, stream>>>(x, k_out, xq);

  // 4) projections
  gemm256<true><<<dim3(16, 16), blk512, 0, stream>>>(
      xq, wqT, qh, 2048, 2048, 2048, 2048);
  gemm_bt<true, false><<<dim3(4, 32), blk, 0, stream>>>(
      xq, wkT, kh, 2048, 2048, 2048, 512, 1.0f);
  gemm_bt<true, true><<<dim3(4, 32), blk, 0, stream>>>(
      xb, wvT, vhT, 2048, 2048, 2048, 4096, 1.0f);

  // 5) fused scores + softmax + attn write + PV -> ctx
  kattn<<<dim3(128, 32), blk512, 0, stream>>>(qh, kh, vhT, attn, ctx);

  // 6) attn_out = ctx @ wo (f32)
  gemm256<false><<<dim3(16, 16), blk512, 0, stream>>>(
      ctx, woT, (void*)ao, 2048, 2048, 2048, 2048);
  // 7) x1b = rmsnorm(x + ao) * n1w
  krms1<<<4096, blk, 0, stream>>>(x, ao, n1w, x1b);
  // 8) h = u * gelu(gate)  (fused dual GEMM, uv never materialized)
  gemm_geglu256<<<dim3(64, 16), blk512, 0, stream>>>(
      x1b, w1T, w1T + 16777216, hbuf, 2048, 2048, 2048, 8192);
  // 9) fc = h @ w2
  gemm256<true><<<dim3(16, 16), blk512, 0, stream>>>(
      hbuf, w2T, fc, 8192, 8192, 8192, 2048);
  // 10) x2 = rmsnorm(x1 + fc) * n2w
  krms2<<<4096, blk, 0, stream>>>(x1b, fc, n2w, x2_out);
}

// Round 9
// 1182.472 us; speedup vs baseline: 1.1688x; 1.0541x over previous
//
#include <hip/hip_runtime.h>
#include <hip/hip_bf16.h>

// ---------------------------------------------------------------------------
// TransformerBlock: B=2 N=2048 E=2048 H=16 G=4 D=128 HID=8192
// out = [ x2 (8.39M f32) | k_flat (8.39M) | v_flat (8.39M) | attn (134.2M) ]
// R8 (re-run; R8 bench was lost to an infra failure): kattn v4 — barrier-free
//     wave-private async pipelines. R7 had 80 block-wide barriers (vmcnt(0)
//     drain each); but K/V staging is wave-private -> replace with counted
//     s_waitcnt vmcnt(4)/(1) per wave (T3/T4), sched_barrier fences,
//     lgkmcnt(0) before buffer reuse. 3 barriers total.
// ---------------------------------------------------------------------------

using f32x4  = __attribute__((ext_vector_type(4))) float;
using bf16x8 = __attribute__((ext_vector_type(8))) short;
using bf16x4 = __attribute__((ext_vector_type(4))) short;
using u16x4  = __attribute__((ext_vector_type(4))) unsigned short;

#define DEV __device__ __forceinline__

// async global->LDS, 16B per lane; LDS dest must be wave-uniform base + lane*16
#define ASYNC16(lds, g)                                                        \
  __builtin_amdgcn_global_load_lds(                                           \
      (const __attribute__((address_space(1))) void*)(g),                      \
      (__attribute__((address_space(3))) void*)(lds), 16, 0, 0)

DEV unsigned short f2bf(float f) {
  unsigned int u = __float_as_uint(f);
  return (unsigned short)((u + 0x7fffu + ((u >> 16) & 1u)) >> 16);
}
DEV float bf2f(unsigned short h) {
  return __uint_as_float(((unsigned int)h) << 16);
}

DEV float waveRedSum(float v) {
#pragma unroll
  for (int o = 32; o; o >>= 1) v += __shfl_xor(v, o);
  return v;
}

// ---- transpose+convert: in f32 [K,N] -> out bf16 [N,K] ---------------------
__global__ __launch_bounds__(256) void kconvT(const float* __restrict__ in,
                                              unsigned short* __restrict__ out,
                                              int K, int N) {
  __shared__ float tile[32][33];
  int bx = blockIdx.x * 32;  // N dim
  int by = blockIdx.y * 32;  // K dim
  int tx = threadIdx.x & 31;
  int ty = threadIdx.x >> 5;  // 0..7
#pragma unroll
  for (int i = 0; i < 32; i += 8)
    tile[ty + i][tx] = in[(size_t)(by + ty + i) * N + bx + tx];
  __syncthreads();
#pragma unroll
  for (int i = 0; i < 32; i += 8)
    out[(size_t)(bx + ty + i) * K + by + tx] = f2bf(tile[tx][ty + i]);
}

// ---- v_flat = x (f32 copy) and x_bf16 --------------------------------------
__global__ __launch_bounds__(256) void kcopy(const f32x4* __restrict__ x,
                                             f32x4* __restrict__ v,
                                             u16x4* __restrict__ xb) {
  int i = blockIdx.x * 256 + threadIdx.x;  // exactly 2,097,152 threads
  f32x4 val = x[i];
  v[i] = val;
  u16x4 o;
  o[0] = f2bf(val[0]); o[1] = f2bf(val[1]); o[2] = f2bf(val[2]); o[3] = f2bf(val[3]);
  xb[i] = o;
}

// ---- RoPE on per-head slices of x -> k_flat f32 (d_out) + xq bf16 ----------
__global__ __launch_bounds__(256) void krope(const float* __restrict__ x,
                                             float* __restrict__ kout,
                                             unsigned short* __restrict__ xq) {
  int idx = blockIdx.x * 256 + threadIdx.x;  // B*N*H*64 = 4,194,304
  int f  = idx & 63;
  int h  = (idx >> 6) & 15;
  int bn = idx >> 10;          // b*2048+n
  int n  = bn & 2047;
  size_t base = (size_t)bn * 2048 + h * 128;
  float inv = exp2f((float)f * (-13.287712379549449f / 64.0f));
  float ang = (float)n * inv;
  float c = cosf(ang), s = sinf(ang);
  float a = x[base + f], b = x[base + f + 64];
  float k1 = a * c - b * s;
  float k2 = b * c + a * s;
  kout[base + f]      = k1;
  kout[base + f + 64] = k2;
  xq[base + f]      = f2bf(k1);
  xq[base + f + 64] = f2bf(k2);
}

// ---- x1b = bf16(rmsnorm(x + ao) * w) ---------------------------------------
__global__ __launch_bounds__(256) void krms1(const float* __restrict__ x,
                                             const float* __restrict__ ao,
                                             const float* __restrict__ w,
                                             unsigned short* __restrict__ x1b) {
  size_t row = blockIdx.x;
  const f32x4* xp = (const f32x4*)(x + row * 2048);
  const f32x4* ap = (const f32x4*)(ao + row * 2048);
  int tid = threadIdx.x;
  f32x4 t0 = xp[tid * 2] + ap[tid * 2];
  f32x4 t1 = xp[tid * 2 + 1] + ap[tid * 2 + 1];
  float ss = 0.f;
#pragma unroll
  for (int i = 0; i < 4; ++i) ss += t0[i] * t0[i] + t1[i] * t1[i];
  ss = waveRedSum(ss);
  __shared__ float red[4];
  int wid = tid >> 6, lane = tid & 63;
  if (!lane) red[wid] = ss;
  __syncthreads();
  ss = red[0] + red[1] + red[2] + red[3];
  float rr = rsqrtf(ss * (1.0f / 2048.0f) + 1e-6f);
  const f32x4* wp = (const f32x4*)w;
  f32x4 w0 = wp[tid * 2], w1 = wp[tid * 2 + 1];
  u16x4 o0, o1;
#pragma unroll
  for (int i = 0; i < 4; ++i) {
    o0[i] = f2bf(t0[i] * rr * w0[i]);
    o1[i] = f2bf(t1[i] * rr * w1[i]);
  }
  u16x4* op = (u16x4*)(x1b + row * 2048);
  op[tid * 2] = o0;
  op[tid * 2 + 1] = o1;
}

// ---- x2 = f32(rmsnorm(x1b + fc) * w) -> d_out ------------------------------
__global__ __launch_bounds__(256) void krms2(const unsigned short* __restrict__ x1b,
                                             const unsigned short* __restrict__ fc,
                                             const float* __restrict__ w,
                                             float* __restrict__ out) {
  size_t row = blockIdx.x;
  const u16x4* xp = (const u16x4*)(x1b + row * 2048);
  const u16x4* fp = (const u16x4*)(fc + row * 2048);
  int tid = threadIdx.x;
  u16x4 a0 = xp[tid * 2], a1 = xp[tid * 2 + 1];
  u16x4 b0 = fp[tid * 2], b1 = fp[tid * 2 + 1];
  f32x4 t0, t1;
#pragma unroll
  for (int i = 0; i < 4; ++i) {
    t0[i] = bf2f(a0[i]) + bf2f(b0[i]);
    t1[i] = bf2f(a1[i]) + bf2f(b1[i]);
  }
  float ss = 0.f;
#pragma unroll
  for (int i = 0; i < 4; ++i) ss += t0[i] * t0[i] + t1[i] * t1[i];
  ss = waveRedSum(ss);
  __shared__ float red[4];
  int wid = tid >> 6, lane = tid & 63;
  if (!lane) red[wid] = ss;
  __syncthreads();
  ss = red[0] + red[1] + red[2] + red[3];
  float rr = rsqrtf(ss * (1.0f / 2048.0f) + 1e-6f);
  const f32x4* wp = (const f32x4*)w;
  f32x4 w0 = wp[tid * 2], w1 = wp[tid * 2 + 1];
  f32x4* op = (f32x4*)(out + row * 2048);
  op[tid * 2]     = t0 * rr * w0;
  op[tid * 2 + 1] = t1 * rr * w1;
}

// ---- 128x128 MFMA GEMM (small shapes: k/v projections) ---------------------
template <bool OUT_BF16, bool TRANS_OUT>
__global__ __launch_bounds__(256, 2) void gemm_bt(
    const unsigned short* __restrict__ A, const unsigned short* __restrict__ Bt,
    void* __restrict__ C_, int K, int lda, int ldb, int ldc, float alpha) {
  __shared__ unsigned short As[128 * 32];
  __shared__ unsigned short Bs[128 * 32];
  const int tid = threadIdx.x;
  const int bm0 = blockIdx.y * 128, bn0 = blockIdx.x * 128;

  f32x4 acc[4][4] = {};

  const int lane = tid & 63, wid = tid >> 6;
  const int wr = wid >> 1, wc = wid & 1;
  const int lr = lane & 15, kq = lane >> 4;
  const int srow = tid >> 2;        // 0..63
  const int scol = (tid & 3) * 8;   // 0,8,16,24
  unsigned short* AsW = As + tid * 8;
  unsigned short* BsW = Bs + tid * 8;

  for (int kt = 0; kt < K; kt += 32) {
    ASYNC16(AsW,        A + (size_t)(bm0 + srow)      * lda + kt + scol);
    ASYNC16(AsW + 2048, A + (size_t)(bm0 + srow + 64) * lda + kt + scol);
    ASYNC16(BsW,        Bt + (size_t)(bn0 + srow)      * ldb + kt + scol);
    ASYNC16(BsW + 2048, Bt + (size_t)(bn0 + srow + 64) * ldb + kt + scol);
    __syncthreads();
    bf16x8 afr[4], bfr[4];
#pragma unroll
    for (int i = 0; i < 4; ++i)
      afr[i] = *(const bf16x8*)&As[(wr * 64 + i * 16 + lr) * 32 + kq * 8];
#pragma unroll
    for (int j = 0; j < 4; ++j)
      bfr[j] = *(const bf16x8*)&Bs[(wc * 64 + j * 16 + lr) * 32 + kq * 8];
#pragma unroll
    for (int i = 0; i < 4; ++i)
#pragma unroll
      for (int j = 0; j < 4; ++j)
        acc[i][j] = __builtin_amdgcn_mfma_f32_16x16x32_bf16(afr[i], bfr[j],
                                                            acc[i][j], 0, 0, 0);
    __syncthreads();
  }

#pragma unroll
  for (int i = 0; i < 4; ++i)
#pragma unroll
    for (int j = 0; j < 4; ++j) {
      int rowb = bm0 + wr * 64 + i * 16 + kq * 4;
      int col = bn0 + wc * 64 + j * 16 + lr;
#pragma unroll
      for (int r = 0; r < 4; ++r) {
        float v = acc[i][j][r] * alpha;
        size_t idx = TRANS_OUT ? ((size_t)col * ldc + (rowb + r))
                               : ((size_t)(rowb + r) * ldc + col);
        if constexpr (OUT_BF16)
          ((unsigned short*)C_)[idx] = f2bf(v);
        else
          ((float*)C_)[idx] = v;
      }
    }
}

// ===========================================================================
// Fused attention v4: barrier-free wave-private async pipelines.
// 8 waves (512 thr), 16 q-rows per block, wave w owns 16-key strips (scores)
// and 16 d-rows (PV). LDS (80KB = 2 blocks/CU):
//   U[64KB] : scores = per-wave K dbuf (2 x 4KB/wave); PV = P[16q][2048k] bf16
//   Vb[16KB]: softmax = redm/reds; PV = per-wave V dbuf (2 x 1KB/wave)
// Counted vmcnt pipelines (loads never drain to 0 mid-loop); 3 barriers total.
// Swizzles (involution on both sides): K chunk c^=(row&7), V chunk c^=(d&3),
// P chunk c8^=(q&7).
// ===========================================================================
__global__ __launch_bounds__(512, 4) void kattn(
    const unsigned short* __restrict__ qh,   // [b][n][h*128+d] ld 2048
    const unsigned short* __restrict__ kh,   // [b][n][g*128+d] ld 512
    const unsigned short* __restrict__ vT,   // [g*128+d][b*2048+key] ld 4096
    float* __restrict__ attn,                // [b][h][q][key]
    unsigned short* __restrict__ ctx) {      // [b][n][h*128+d] ld 2048
  __shared__ __align__(16) char U[65536];
  __shared__ __align__(16) char Vb[16384];
  float* redm = (float*)Vb;         // [8][16]
  float* reds = redm + 128;         // [8][16]

  const int tid = threadIdx.x;
  const int lane = tid & 63, w = tid >> 6;   // w 0..7
  const int lr = lane & 15, kq = lane >> 4;  // q = lr, quarter = kq
  const int z = blockIdx.y, bz = z >> 4, hz = z & 15;
  const int q0 = blockIdx.x * 16;

  // Q fragments (B-operand): Q[q=lr][k], k-contiguous
  const unsigned short* Aq =
      qh + ((size_t)(bz * 2048 + q0 + lr) * 2048 + hz * 128);
  bf16x8 qfr[4];
#pragma unroll
  for (int kk = 0; kk < 4; ++kk)
    qfr[kk] = *(const bf16x8*)(Aq + kk * 32 + kq * 8);

  // --- scores: wave-private K staging, counted-vmcnt pipeline --------------
  const unsigned short* Kb =
      kh + ((size_t)(bz * 2048) * 512 + (hz >> 2) * 128);
  // per lane 4 slots/tile: idx = R*64+lane -> local row idx>>4, chunk idx&15
  int krow[4], kcs[4];
#pragma unroll
  for (int R = 0; R < 4; ++R) {
    int idx = R * 64 + lane;
    krow[R] = idx >> 4;
    kcs[R] = (idx & 15) ^ (krow[R] & 7);  // pre-swizzled source chunk
  }
  auto stageK = [&](int buf, int t) {
#pragma unroll
    for (int R = 0; R < 4; ++R)
      ASYNC16(U + buf * 32768 + w * 4096 + (R * 64 + lane) * 16,
              Kb + (size_t)(t * 128 + w * 16 + krow[R]) * 512 + kcs[R] * 8);
  };

  f32x4 acc[16];
#pragma unroll
  for (int t = 0; t < 16; ++t) acc[t] = f32x4{0.f, 0.f, 0.f, 0.f};

  stageK(0, 0);
  stageK(1, 1);
#pragma unroll
  for (int t = 0; t < 16; ++t) {
    if (t < 15) asm volatile("s_waitcnt vmcnt(4)" ::: "memory");
    else        asm volatile("s_waitcnt vmcnt(0)" ::: "memory");
    __builtin_amdgcn_sched_barrier(0);
    const char* Kw = U + (t & 1) * 32768 + w * 4096;
    bf16x8 kfr[4];
#pragma unroll
    for (int kk = 0; kk < 4; ++kk) {
      int cch = (kk * 4 + kq) ^ (lr & 7);
      kfr[kk] = *(const bf16x8*)(Kw + lr * 256 + cch * 16);
    }
    asm volatile("s_waitcnt lgkmcnt(0)" ::: "memory");
    __builtin_amdgcn_sched_barrier(0);
    if (t + 2 < 16) stageK(t & 1, t + 2);  // reuse just-read buffer
#pragma unroll
    for (int kk = 0; kk < 4; ++kk)
      acc[t] = __builtin_amdgcn_mfma_f32_16x16x32_bf16(kfr[kk], qfr[kk],
                                                       acc[t], 0, 0, 0);
  }

  // --- softmax (per-lane q-row = lr) ---------------------------------------
  const float scale = 0.08838834764831845f;
  float mx = -3.4e38f;
#pragma unroll
  for (int t = 0; t < 16; ++t) {
    acc[t] *= scale;
#pragma unroll
    for (int r = 0; r < 4; ++r) mx = fmaxf(mx, acc[t][r]);
  }
  mx = fmaxf(mx, __shfl_xor(mx, 16));
  mx = fmaxf(mx, __shfl_xor(mx, 32));
  if (kq == 0) redm[w * 16 + lr] = mx;
  __syncthreads();  // barrier A
  mx = redm[lr];
#pragma unroll
  for (int ww = 1; ww < 8; ++ww) mx = fmaxf(mx, redm[ww * 16 + lr]);

  float sm = 0.f;
#pragma unroll
  for (int t = 0; t < 16; ++t) {
#pragma unroll
    for (int r = 0; r < 4; ++r) {
      float e = __expf(acc[t][r] - mx);
      acc[t][r] = e;
      sm += e;
    }
  }
  sm += __shfl_xor(sm, 16);
  sm += __shfl_xor(sm, 32);
  if (kq == 0) reds[w * 16 + lr] = sm;
  __syncthreads();  // barrier B
  float smt = reds[lr];
#pragma unroll
  for (int ww = 1; ww < 8; ++ww) smt += reds[ww * 16 + lr];
  float inv = 1.0f / smt;

  // --- write attn f32 + P bf16 into U (K staging done; swizzled chunks) ----
  float* arow = attn + (((size_t)z * 2048 + q0 + lr) * 2048);
#pragma unroll
  for (int t = 0; t < 16; ++t) {
    int key = t * 128 + w * 16 + kq * 4;
    f32x4 p = acc[t] * inv;
    *(f32x4*)(arow + key) = p;
    bf16x4 pb;
#pragma unroll
    for (int r = 0; r < 4; ++r) pb[r] = (short)f2bf(p[r]);
    int c8 = key >> 3;  // 16B chunk index in q-row
    *(bf16x4*)(U + lr * 4096 + ((c8 ^ (lr & 7)) << 4) + ((key & 7) << 1)) = pb;
  }
  __syncthreads();  // barrier C: P ready, red reads done, stores drained

  // --- PV: wave-private V staging, counted-vmcnt pipeline ------------------
  const unsigned short* Bv = vT + (size_t)(hz >> 2) * 524288 + bz * 2048;
  const int d0 = w * 16;
  const int vd = lane >> 2;                 // 0..15 local d-row
  const int vcs = (lane & 3) ^ (vd & 3);    // pre-swizzled source chunk
  auto stageV = [&](int buf, int t) {
    ASYNC16(Vb + buf * 8192 + w * 1024 + lane * 16,
            Bv + (size_t)(d0 + vd) * 4096 + t * 32 + vcs * 8);
  };

  f32x4 cfr = {};
  stageV(0, 0);
  stageV(1, 1);
#pragma unroll
  for (int t = 0; t < 64; ++t) {
    if (t < 63) asm volatile("s_waitcnt vmcnt(1)" ::: "memory");
    else        asm volatile("s_waitcnt vmcnt(0)" ::: "memory");
    __builtin_amdgcn_sched_barrier(0);
    int c8 = t * 4 + kq;
    bf16x8 pfr = *(const bf16x8*)(U + lr * 4096 + ((c8 ^ (lr & 7)) << 4));
    const char* Vw = Vb + (t & 1) * 8192 + w * 1024;
    bf16x8 vfr = *(const bf16x8*)(Vw + lr * 64 + ((kq ^ (lr & 3)) << 4));
    asm volatile("s_waitcnt lgkmcnt(0)" ::: "memory");
    __builtin_amdgcn_sched_barrier(0);
    if (t + 2 < 64) stageV(t & 1, t + 2);  // reuse just-read buffer
    cfr = __builtin_amdgcn_mfma_f32_16x16x32_bf16(pfr, vfr, cfr, 0, 0, 0);
  }
#pragma unroll
  for (int r = 0; r < 4; ++r) {
    int q = kq * 4 + r;
    ctx[((size_t)(bz * 2048 + q0 + q) * 2048) + hz * 128 + d0 + lr] =
        f2bf(cfr[r]);
  }
}

// ===========================================================================
// 256x128 8-wave double-buffered GEMM, BK=64 (front-loaded gll16 + swizzle)
// ===========================================================================
template <bool OUT_BF16>
__global__ __launch_bounds__(512, 2) void gemm256(
    const unsigned short* __restrict__ A, const unsigned short* __restrict__ Bt,
    void* __restrict__ C_, int K, int lda, int ldb, int ldc) {
  __shared__ unsigned short As[2][256 * 64];  // 64 KB
  __shared__ unsigned short Bs[2][128 * 64];  // 32 KB
  const int tid = threadIdx.x;
  const int bm0 = blockIdx.y * 256, bn0 = blockIdx.x * 128;
  const int lane = tid & 63, wid = tid >> 6;
  const int wr = wid >> 2, wc = wid & 3;
  const int lr = lane & 15, kq = lane >> 4;

  f32x4 acc[8][2] = {};

  int sArow[4], sAcc[4], sBrow[2], sBcc[2];
#pragma unroll
  for (int R = 0; R < 4; ++R) {
    int c = R * 512 + tid;
    sArow[R] = c >> 3;
    sAcc[R]  = (c & 7) ^ (sArow[R] & 7);
  }
#pragma unroll
  for (int R = 0; R < 2; ++R) {
    int c = R * 512 + tid;
    sBrow[R] = c >> 3;
    sBcc[R]  = (c & 7) ^ (sBrow[R] & 7);
  }

  auto stage = [&](int buf, int k0) {
#pragma unroll
    for (int R = 0; R < 4; ++R)
      ASYNC16(&As[buf][(R * 512 + tid) * 8],
              A + (size_t)(bm0 + sArow[R]) * lda + k0 + sAcc[R] * 8);
#pragma unroll
    for (int R = 0; R < 2; ++R)
      ASYNC16(&Bs[buf][(R * 512 + tid) * 8],
              Bt + (size_t)(bn0 + sBrow[R]) * ldb + k0 + sBcc[R] * 8);
  };

  const int NT = K >> 6;
  stage(0, 0);
  __syncthreads();
  int cur = 0;
  for (int t = 0; t < NT; ++t) {
    if (t + 1 < NT) stage(cur ^ 1, (t + 1) << 6);
    const unsigned short* Ac = As[cur];
    const unsigned short* Bc = Bs[cur];
    __builtin_amdgcn_s_setprio(1);
#pragma unroll
    for (int ks = 0; ks < 2; ++ks) {
      bf16x8 afr[8];
#pragma unroll
      for (int i = 0; i < 8; ++i) {
        int row = wr * 128 + i * 16 + lr;
        int cch = (ks * 4 + kq) ^ (row & 7);
        afr[i] = *(const bf16x8*)&Ac[(row * 8 + cch) * 8];
      }
#pragma unroll
      for (int j = 0; j < 2; ++j) {
        int brow = wc * 32 + j * 16 + lr;
        int cch = (ks * 4 + kq) ^ (brow & 7);
        bf16x8 bfr = *(const bf16x8*)&Bc[(brow * 8 + cch) * 8];
#pragma unroll
        for (int i = 0; i < 8; ++i)
          acc[i][j] = __builtin_amdgcn_mfma_f32_16x16x32_bf16(afr[i], bfr,
                                                              acc[i][j], 0, 0, 0);
      }
    }
    __builtin_amdgcn_s_setprio(0);
    __syncthreads();
    cur ^= 1;
  }

#pragma unroll
  for (int i = 0; i < 8; ++i)
#pragma unroll
    for (int j = 0; j < 2; ++j) {
      int rowb = bm0 + wr * 128 + i * 16 + kq * 4;
      int col = bn0 + wc * 32 + j * 16 + lr;
#pragma unroll
      for (int r = 0; r < 4; ++r) {
        if constexpr (OUT_BF16)
          ((unsigned short*)C_)[(size_t)(rowb + r) * ldc + col] = f2bf(acc[i][j][r]);
        else
          ((float*)C_)[(size_t)(rowb + r) * ldc + col] = acc[i][j][r];
      }
    }
}

// ---- same structure, dual-B GeGLU: h = (A@B1^T) * gelu(A@B2^T) -------------
__global__ __launch_bounds__(512, 2) void gemm_geglu256(
    const unsigned short* __restrict__ A, const unsigned short* __restrict__ B1,
    const unsigned short* __restrict__ B2, unsigned short* __restrict__ H_,
    int K, int lda, int ldb, int ldc) {
  __shared__ unsigned short As[2][256 * 64];   // 64 KB
  __shared__ unsigned short B1s[2][128 * 64];  // 32 KB
  __shared__ unsigned short B2s[2][128 * 64];  // 32 KB
  const int tid = threadIdx.x;
  const int bm0 = blockIdx.y * 256, bn0 = blockIdx.x * 128;
  const int lane = tid & 63, wid = tid >> 6;
  const int wr = wid >> 2, wc = wid & 3;
  const int lr = lane & 15, kq = lane >> 4;

  f32x4 accu[8][2] = {};
  f32x4 accg[8][2] = {};

  int sArow[4], sAcc[4], sBrow[2], sBcc[2];
#pragma unroll
  for (int R = 0; R < 4; ++R) {
    int c = R * 512 + tid;
    sArow[R] = c >> 3;
    sAcc[R]  = (c & 7) ^ (sArow[R] & 7);
  }
#pragma unroll
  for (int R = 0; R < 2; ++R) {
    int c = R * 512 + tid;
    sBrow[R] = c >> 3;
    sBcc[R]  = (c & 7) ^ (sBrow[R] & 7);
  }

  auto stage = [&](int buf, int k0) {
#pragma unroll
    for (int R = 0; R < 4; ++R)
      ASYNC16(&As[buf][(R * 512 + tid) * 8],
              A + (size_t)(bm0 + sArow[R]) * lda + k0 + sAcc[R] * 8);
#pragma unroll
    for (int R = 0; R < 2; ++R)
      ASYNC16(&B1s[buf][(R * 512 + tid) * 8],
              B1 + (size_t)(bn0 + sBrow[R]) * ldb + k0 + sBcc[R] * 8);
#pragma unroll
    for (int R = 0; R < 2; ++R)
      ASYNC16(&B2s[buf][(R * 512 + tid) * 8],
              B2 + (size_t)(bn0 + sBrow[R]) * ldb + k0 + sBcc[R] * 8);
  };

  const int NT = K >> 6;
  stage(0, 0);
  __syncthreads();
  int cur = 0;
  for (int t = 0; t < NT; ++t) {
    if (t + 1 < NT) stage(cur ^ 1, (t + 1) << 6);
    const unsigned short* Ac = As[cur];
    const unsigned short* B1c = B1s[cur];
    const unsigned short* B2c = B2s[cur];
    __builtin_amdgcn_s_setprio(1);
#pragma unroll
    for (int ks = 0; ks < 2; ++ks) {
      bf16x8 afr[8];
#pragma unroll
      for (int i = 0; i < 8; ++i) {
        int row = wr * 128 + i * 16 + lr;
        int cch = (ks * 4 + kq) ^ (row & 7);
        afr[i] = *(const bf16x8*)&Ac[(row * 8 + cch) * 8];
      }
#pragma unroll
      for (int j = 0; j < 2; ++j) {
        int brow = wc * 32 + j * 16 + lr;
        int cch = (ks * 4 + kq) ^ (brow & 7);
        bf16x8 b1 = *(const bf16x8*)&B1c[(brow * 8 + cch) * 8];
        bf16x8 b2 = *(const bf16x8*)&B2c[(brow * 8 + cch) * 8];
#pragma unroll
        for (int i = 0; i < 8; ++i) {
          accu[i][j] = __builtin_amdgcn_mfma_f32_16x16x32_bf16(afr[i], b1,
                                                               accu[i][j], 0, 0, 0);
          accg[i][j] = __builtin_amdgcn_mfma_f32_16x16x32_bf16(afr[i], b2,
                                                               accg[i][j], 0, 0, 0);
        }
      }
    }
    __builtin_amdgcn_s_setprio(0);
    __syncthreads();
    cur ^= 1;
  }

#pragma unroll
  for (int i = 0; i < 8; ++i)
#pragma unroll
    for (int j = 0; j < 2; ++j) {
      int rowb = bm0 + wr * 128 + i * 16 + kq * 4;
      int col = bn0 + wc * 32 + j * 16 + lr;
#pragma unroll
      for (int r = 0; r < 4; ++r) {
        float u = accu[i][j][r];
        float g = accg[i][j][r];
        float tv = tanhf(0.7978845608028654f * (g + 0.044715f * g * g * g));
        float hv = u * 0.5f * g * (1.0f + tv);
        H_[(size_t)(rowb + r) * ldc + col] = f2bf(hv);
      }
    }
}

// ---------------------------------------------------------------------------
extern "C" void kernel_launch(void* const* d_in, const int* in_sizes, int n_in,
                              void* d_out, int out_size, void* d_ws, size_t ws_size,
                              hipStream_t stream) {
  const float* x   = (const float*)d_in[0];
  const float* wq  = (const float*)d_in[1];
  const float* wk  = (const float*)d_in[2];
  const float* wv  = (const float*)d_in[3];
  const float* wo  = (const float*)d_in[4];
  const float* w1  = (const float*)d_in[5];
  const float* w2  = (const float*)d_in[6];
  const float* n1w = (const float*)d_in[7];
  const float* n2w = (const float*)d_in[8];

  float* out    = (float*)d_out;
  float* x2_out = out;
  float* k_out  = out + 8388608;
  float* v_out  = out + 16777216;
  float* attn   = out + 25165824;  // 134,217,728 f32

  char* ws = (char*)d_ws;
  unsigned short* wqT  = (unsigned short*)(ws + 0);
  unsigned short* wkT  = (unsigned short*)(ws + 8388608);
  unsigned short* wvT  = (unsigned short*)(ws + 10485760);
  unsigned short* woT  = (unsigned short*)(ws + 12582912);
  unsigned short* w1T  = (unsigned short*)(ws + 20971520);
  unsigned short* w2T  = (unsigned short*)(ws + 88080384);
  unsigned short* qh   = (unsigned short*)(ws + 121634816);
  unsigned short* kh   = (unsigned short*)(ws + 138412032);
  unsigned short* vhT  = (unsigned short*)(ws + 142606336);
  unsigned short* ctx  = (unsigned short*)(ws + 146800640);
  float*          ao   = (float*)(ws + 163577856);
  unsigned short* hbuf = (unsigned short*)(ws + 121634816);  // alias qh..ao (dead)
  unsigned short* x1b  = (unsigned short*)(ws + 197132288);
  unsigned short* fc   = (unsigned short*)(ws + 213909504);
  // ws total: 230,686,720 bytes

  // bf16 scratch inside not-yet-written attn region of d_out
  unsigned short* xb = (unsigned short*)attn;   // bf16(x), 8,388,608 elems
  unsigned short* xq = xb + 8388608;            // bf16(rope(x))

  dim3 blk(256);
  dim3 blk512(512);

  // 1) weight convert+transpose (f32 [K,N] -> bf16 [N,K])
  kconvT<<<dim3(64, 64), blk, 0, stream>>>(wq, wqT, 2048, 2048);
  kconvT<<<dim3(16, 64), blk, 0, stream>>>(wk, wkT, 2048, 512);
  kconvT<<<dim3(16, 64), blk, 0, stream>>>(wv, wvT, 2048, 512);
  kconvT<<<dim3(64, 64), blk, 0, stream>>>(wo, woT, 2048, 2048);
  kconvT<<<dim3(512, 64), blk, 0, stream>>>(w1, w1T, 2048, 16384);
  kconvT<<<dim3(64, 256), blk, 0, stream>>>(w2, w2T, 8192, 2048);

  // 2) v_flat = x ; xb = bf16(x)
  kcopy<<<8192, blk, 0, stream>>>((const f32x4*)x, (f32x4*)v_out, (u16x4*)xb);
  // 3) k_flat = rope(x) f32 ; xq = bf16(rope(x))
  krope<<<16384, blk, 0, stream>>>(x, k_out, xq);

  // 4) projections
  gemm256<true><<<dim3(16, 16), blk512, 0, stream>>>(
      xq, wqT, qh, 2048, 2048, 2048, 2048);
  gemm_bt<true, false><<<dim3(4, 32), blk, 0, stream>>>(
      xq, wkT, kh, 2048, 2048, 2048, 512, 1.0f);
  gemm_bt<true, true><<<dim3(4, 32), blk, 0, stream>>>(
      xb, wvT, vhT, 2048, 2048, 2048, 4096, 1.0f);

  // 5) fused scores + softmax + attn write + PV -> ctx
  kattn<<<dim3(128, 32), blk512, 0, stream>>>(qh, kh, vhT, attn, ctx);

  // 6) attn_out = ctx @ wo (f32)
  gemm256<false><<<dim3(16, 16), blk512, 0, stream>>>(
      ctx, woT, (void*)ao, 2048, 2048, 2048, 2048);
  // 7) x1b = rmsnorm(x + ao) * n1w
  krms1<<<4096, blk, 0, stream>>>(x, ao, n1w, x1b);
  // 8) h = u * gelu(gate)  (fused dual GEMM, uv never materialized)
  gemm_geglu256<<<dim3(64, 16), blk512, 0, stream>>>(
      x1b, w1T, w1T + 16777216, hbuf, 2048, 2048, 2048, 8192);
  // 9) fc = h @ w2
  gemm256<true><<<dim3(16, 16), blk512, 0, stream>>>(
      hbuf, w2T, fc, 8192, 8192, 8192, 2048);
  // 10) x2 = rmsnorm(x1 + fc) * n2w
  krms2<<<4096, blk, 0, stream>>>(x1b, fc, n2w, x2_out);
}

// Round 10
// 1114.071 us; speedup vs baseline: 1.2405x; 1.0614x over previous
//
#include <hip/hip_runtime.h>
#include <hip/hip_bf16.h>

// ---------------------------------------------------------------------------
// TransformerBlock: B=2 N=2048 E=2048 H=16 G=4 D=128 HID=8192
// out = [ x2 (8.39M f32) | k_flat (8.39M) | v_flat (8.39M) | attn (134.2M) ]
// R10: kattn v5 — XCD-locality swizzle. 8 (b,g) slices == 8 XCDs; K+V per
//      slice = 4MB == one XCD L2. g8 = bid&7 pins each slice's 512 blocks to
//      one XCD (round-robin dispatch heuristic) -> K/V re-reads become L2
//      hits (~200cy) that the v4 2-deep counted-vmcnt pipeline CAN hide.
// ---------------------------------------------------------------------------

using f32x4  = __attribute__((ext_vector_type(4))) float;
using bf16x8 = __attribute__((ext_vector_type(8))) short;
using bf16x4 = __attribute__((ext_vector_type(4))) short;
using u16x4  = __attribute__((ext_vector_type(4))) unsigned short;

#define DEV __device__ __forceinline__

// async global->LDS, 16B per lane; LDS dest must be wave-uniform base + lane*16
#define ASYNC16(lds, g)                                                        \
  __builtin_amdgcn_global_load_lds(                                           \
      (const __attribute__((address_space(1))) void*)(g),                      \
      (__attribute__((address_space(3))) void*)(lds), 16, 0, 0)

DEV unsigned short f2bf(float f) {
  unsigned int u = __float_as_uint(f);
  return (unsigned short)((u + 0x7fffu + ((u >> 16) & 1u)) >> 16);
}
DEV float bf2f(unsigned short h) {
  return __uint_as_float(((unsigned int)h) << 16);
}

DEV float waveRedSum(float v) {
#pragma unroll
  for (int o = 32; o; o >>= 1) v += __shfl_xor(v, o);
  return v;
}

// ---- transpose+convert: in f32 [K,N] -> out bf16 [N,K] ---------------------
__global__ __launch_bounds__(256) void kconvT(const float* __restrict__ in,
                                              unsigned short* __restrict__ out,
                                              int K, int N) {
  __shared__ float tile[32][33];
  int bx = blockIdx.x * 32;  // N dim
  int by = blockIdx.y * 32;  // K dim
  int tx = threadIdx.x & 31;
  int ty = threadIdx.x >> 5;  // 0..7
#pragma unroll
  for (int i = 0; i < 32; i += 8)
    tile[ty + i][tx] = in[(size_t)(by + ty + i) * N + bx + tx];
  __syncthreads();
#pragma unroll
  for (int i = 0; i < 32; i += 8)
    out[(size_t)(bx + ty + i) * K + by + tx] = f2bf(tile[tx][ty + i]);
}

// ---- v_flat = x (f32 copy) and x_bf16 --------------------------------------
__global__ __launch_bounds__(256) void kcopy(const f32x4* __restrict__ x,
                                             f32x4* __restrict__ v,
                                             u16x4* __restrict__ xb) {
  int i = blockIdx.x * 256 + threadIdx.x;  // exactly 2,097,152 threads
  f32x4 val = x[i];
  v[i] = val;
  u16x4 o;
  o[0] = f2bf(val[0]); o[1] = f2bf(val[1]); o[2] = f2bf(val[2]); o[3] = f2bf(val[3]);
  xb[i] = o;
}

// ---- RoPE on per-head slices of x -> k_flat f32 (d_out) + xq bf16 ----------
__global__ __launch_bounds__(256) void krope(const float* __restrict__ x,
                                             float* __restrict__ kout,
                                             unsigned short* __restrict__ xq) {
  int idx = blockIdx.x * 256 + threadIdx.x;  // B*N*H*64 = 4,194,304
  int f  = idx & 63;
  int h  = (idx >> 6) & 15;
  int bn = idx >> 10;          // b*2048+n
  int n  = bn & 2047;
  size_t base = (size_t)bn * 2048 + h * 128;
  float inv = exp2f((float)f * (-13.287712379549449f / 64.0f));
  float ang = (float)n * inv;
  float c = cosf(ang), s = sinf(ang);
  float a = x[base + f], b = x[base + f + 64];
  float k1 = a * c - b * s;
  float k2 = b * c + a * s;
  kout[base + f]      = k1;
  kout[base + f + 64] = k2;
  xq[base + f]      = f2bf(k1);
  xq[base + f + 64] = f2bf(k2);
}

// ---- x1b = bf16(rmsnorm(x + ao) * w) ---------------------------------------
__global__ __launch_bounds__(256) void krms1(const float* __restrict__ x,
                                             const float* __restrict__ ao,
                                             const float* __restrict__ w,
                                             unsigned short* __restrict__ x1b) {
  size_t row = blockIdx.x;
  const f32x4* xp = (const f32x4*)(x + row * 2048);
  const f32x4* ap = (const f32x4*)(ao + row * 2048);
  int tid = threadIdx.x;
  f32x4 t0 = xp[tid * 2] + ap[tid * 2];
  f32x4 t1 = xp[tid * 2 + 1] + ap[tid * 2 + 1];
  float ss = 0.f;
#pragma unroll
  for (int i = 0; i < 4; ++i) ss += t0[i] * t0[i] + t1[i] * t1[i];
  ss = waveRedSum(ss);
  __shared__ float red[4];
  int wid = tid >> 6, lane = tid & 63;
  if (!lane) red[wid] = ss;
  __syncthreads();
  ss = red[0] + red[1] + red[2] + red[3];
  float rr = rsqrtf(ss * (1.0f / 2048.0f) + 1e-6f);
  const f32x4* wp = (const f32x4*)w;
  f32x4 w0 = wp[tid * 2], w1 = wp[tid * 2 + 1];
  u16x4 o0, o1;
#pragma unroll
  for (int i = 0; i < 4; ++i) {
    o0[i] = f2bf(t0[i] * rr * w0[i]);
    o1[i] = f2bf(t1[i] * rr * w1[i]);
  }
  u16x4* op = (u16x4*)(x1b + row * 2048);
  op[tid * 2] = o0;
  op[tid * 2 + 1] = o1;
}

// ---- x2 = f32(rmsnorm(x1b + fc) * w) -> d_out ------------------------------
__global__ __launch_bounds__(256) void krms2(const unsigned short* __restrict__ x1b,
                                             const unsigned short* __restrict__ fc,
                                             const float* __restrict__ w,
                                             float* __restrict__ out) {
  size_t row = blockIdx.x;
  const u16x4* xp = (const u16x4*)(x1b + row * 2048);
  const u16x4* fp = (const u16x4*)(fc + row * 2048);
  int tid = threadIdx.x;
  u16x4 a0 = xp[tid * 2], a1 = xp[tid * 2 + 1];
  u16x4 b0 = fp[tid * 2], b1 = fp[tid * 2 + 1];
  f32x4 t0, t1;
#pragma unroll
  for (int i = 0; i < 4; ++i) {
    t0[i] = bf2f(a0[i]) + bf2f(b0[i]);
    t1[i] = bf2f(a1[i]) + bf2f(b1[i]);
  }
  float ss = 0.f;
#pragma unroll
  for (int i = 0; i < 4; ++i) ss += t0[i] * t0[i] + t1[i] * t1[i];
  ss = waveRedSum(ss);
  __shared__ float red[4];
  int wid = tid >> 6, lane = tid & 63;
  if (!lane) red[wid] = ss;
  __syncthreads();
  ss = red[0] + red[1] + red[2] + red[3];
  float rr = rsqrtf(ss * (1.0f / 2048.0f) + 1e-6f);
  const f32x4* wp = (const f32x4*)w;
  f32x4 w0 = wp[tid * 2], w1 = wp[tid * 2 + 1];
  f32x4* op = (f32x4*)(out + row * 2048);
  op[tid * 2]     = t0 * rr * w0;
  op[tid * 2 + 1] = t1 * rr * w1;
}

// ---- 128x128 MFMA GEMM (small shapes: k/v projections) ---------------------
template <bool OUT_BF16, bool TRANS_OUT>
__global__ __launch_bounds__(256, 2) void gemm_bt(
    const unsigned short* __restrict__ A, const unsigned short* __restrict__ Bt,
    void* __restrict__ C_, int K, int lda, int ldb, int ldc, float alpha) {
  __shared__ unsigned short As[128 * 32];
  __shared__ unsigned short Bs[128 * 32];
  const int tid = threadIdx.x;
  const int bm0 = blockIdx.y * 128, bn0 = blockIdx.x * 128;

  f32x4 acc[4][4] = {};

  const int lane = tid & 63, wid = tid >> 6;
  const int wr = wid >> 1, wc = wid & 1;
  const int lr = lane & 15, kq = lane >> 4;
  const int srow = tid >> 2;        // 0..63
  const int scol = (tid & 3) * 8;   // 0,8,16,24
  unsigned short* AsW = As + tid * 8;
  unsigned short* BsW = Bs + tid * 8;

  for (int kt = 0; kt < K; kt += 32) {
    ASYNC16(AsW,        A + (size_t)(bm0 + srow)      * lda + kt + scol);
    ASYNC16(AsW + 2048, A + (size_t)(bm0 + srow + 64) * lda + kt + scol);
    ASYNC16(BsW,        Bt + (size_t)(bn0 + srow)      * ldb + kt + scol);
    ASYNC16(BsW + 2048, Bt + (size_t)(bn0 + srow + 64) * ldb + kt + scol);
    __syncthreads();
    bf16x8 afr[4], bfr[4];
#pragma unroll
    for (int i = 0; i < 4; ++i)
      afr[i] = *(const bf16x8*)&As[(wr * 64 + i * 16 + lr) * 32 + kq * 8];
#pragma unroll
    for (int j = 0; j < 4; ++j)
      bfr[j] = *(const bf16x8*)&Bs[(wc * 64 + j * 16 + lr) * 32 + kq * 8];
#pragma unroll
    for (int i = 0; i < 4; ++i)
#pragma unroll
      for (int j = 0; j < 4; ++j)
        acc[i][j] = __builtin_amdgcn_mfma_f32_16x16x32_bf16(afr[i], bfr[j],
                                                            acc[i][j], 0, 0, 0);
    __syncthreads();
  }

#pragma unroll
  for (int i = 0; i < 4; ++i)
#pragma unroll
    for (int j = 0; j < 4; ++j) {
      int rowb = bm0 + wr * 64 + i * 16 + kq * 4;
      int col = bn0 + wc * 64 + j * 16 + lr;
#pragma unroll
      for (int r = 0; r < 4; ++r) {
        float v = acc[i][j][r] * alpha;
        size_t idx = TRANS_OUT ? ((size_t)col * ldc + (rowb + r))
                               : ((size_t)(rowb + r) * ldc + col);
        if constexpr (OUT_BF16)
          ((unsigned short*)C_)[idx] = f2bf(v);
        else
          ((float*)C_)[idx] = v;
      }
    }
}

// ===========================================================================
// Fused attention v5: v4 pipeline + XCD-locality block swizzle.
// 1D grid 4096: g8 = bid&7 -> (bz = g8>>2, gz = g8&3) pinned to XCD g8
// (round-robin dispatch); j = bid>>3 -> head-in-group (j&3), q-tile (j>>2).
// Each XCD's K+V slice = 2+2MB == its 4MB L2 -> staged loads become L2 hits
// that the 2-deep counted-vmcnt pipeline can hide.
// LDS (80KB = 2 blocks/CU): U[64KB] K-dbuf then P; Vb[16KB] red then V-dbuf.
// ===========================================================================
__global__ __launch_bounds__(512, 4) void kattn(
    const unsigned short* __restrict__ qh,   // [b][n][h*128+d] ld 2048
    const unsigned short* __restrict__ kh,   // [b][n][g*128+d] ld 512
    const unsigned short* __restrict__ vT,   // [g*128+d][b*2048+key] ld 4096
    float* __restrict__ attn,                // [b][h][q][key]
    unsigned short* __restrict__ ctx) {      // [b][n][h*128+d] ld 2048
  __shared__ __align__(16) char U[65536];
  __shared__ __align__(16) char Vb[16384];
  float* redm = (float*)Vb;         // [8][16]
  float* reds = redm + 128;         // [8][16]

  const int tid = threadIdx.x;
  const int lane = tid & 63, w = tid >> 6;   // w 0..7
  const int lr = lane & 15, kq = lane >> 4;  // q = lr, quarter = kq
  // XCD-locality decode: slice g8 -> XCD g8; j walks heads-in-group, q-tiles
  const int bid = blockIdx.x;
  const int g8 = bid & 7;          // (b,g) slice, 0..7
  const int j  = bid >> 3;         // 0..511
  const int bz = g8 >> 2;          // batch
  const int gz = g8 & 3;           // kv group
  const int hz = gz * 4 + (j & 3); // head (hz>>2 == gz)
  const int q0 = (j >> 2) << 4;    // q-tile * 16
  const int z  = bz * 16 + hz;

  // Q fragments (B-operand): Q[q=lr][k], k-contiguous
  const unsigned short* Aq =
      qh + ((size_t)(bz * 2048 + q0 + lr) * 2048 + hz * 128);
  bf16x8 qfr[4];
#pragma unroll
  for (int kk = 0; kk < 4; ++kk)
    qfr[kk] = *(const bf16x8*)(Aq + kk * 32 + kq * 8);

  // --- scores: wave-private K staging, counted-vmcnt pipeline --------------
  const unsigned short* Kb =
      kh + ((size_t)(bz * 2048) * 512 + gz * 128);
  // per lane 4 slots/tile: idx = R*64+lane -> local row idx>>4, chunk idx&15
  int krow[4], kcs[4];
#pragma unroll
  for (int R = 0; R < 4; ++R) {
    int idx = R * 64 + lane;
    krow[R] = idx >> 4;
    kcs[R] = (idx & 15) ^ (krow[R] & 7);  // pre-swizzled source chunk
  }
  auto stageK = [&](int buf, int t) {
#pragma unroll
    for (int R = 0; R < 4; ++R)
      ASYNC16(U + buf * 32768 + w * 4096 + (R * 64 + lane) * 16,
              Kb + (size_t)(t * 128 + w * 16 + krow[R]) * 512 + kcs[R] * 8);
  };

  f32x4 acc[16];
#pragma unroll
  for (int t = 0; t < 16; ++t) acc[t] = f32x4{0.f, 0.f, 0.f, 0.f};

  stageK(0, 0);
  stageK(1, 1);
#pragma unroll
  for (int t = 0; t < 16; ++t) {
    if (t < 15) asm volatile("s_waitcnt vmcnt(4)" ::: "memory");
    else        asm volatile("s_waitcnt vmcnt(0)" ::: "memory");
    __builtin_amdgcn_sched_barrier(0);
    const char* Kw = U + (t & 1) * 32768 + w * 4096;
    bf16x8 kfr[4];
#pragma unroll
    for (int kk = 0; kk < 4; ++kk) {
      int cch = (kk * 4 + kq) ^ (lr & 7);
      kfr[kk] = *(const bf16x8*)(Kw + lr * 256 + cch * 16);
    }
    asm volatile("s_waitcnt lgkmcnt(0)" ::: "memory");
    __builtin_amdgcn_sched_barrier(0);
    if (t + 2 < 16) stageK(t & 1, t + 2);  // reuse just-read buffer
#pragma unroll
    for (int kk = 0; kk < 4; ++kk)
      acc[t] = __builtin_amdgcn_mfma_f32_16x16x32_bf16(kfr[kk], qfr[kk],
                                                       acc[t], 0, 0, 0);
  }

  // --- softmax (per-lane q-row = lr) ---------------------------------------
  const float scale = 0.08838834764831845f;
  float mx = -3.4e38f;
#pragma unroll
  for (int t = 0; t < 16; ++t) {
    acc[t] *= scale;
#pragma unroll
    for (int r = 0; r < 4; ++r) mx = fmaxf(mx, acc[t][r]);
  }
  mx = fmaxf(mx, __shfl_xor(mx, 16));
  mx = fmaxf(mx, __shfl_xor(mx, 32));
  if (kq == 0) redm[w * 16 + lr] = mx;
  __syncthreads();  // barrier A
  mx = redm[lr];
#pragma unroll
  for (int ww = 1; ww < 8; ++ww) mx = fmaxf(mx, redm[ww * 16 + lr]);

  float sm = 0.f;
#pragma unroll
  for (int t = 0; t < 16; ++t) {
#pragma unroll
    for (int r = 0; r < 4; ++r) {
      float e = __expf(acc[t][r] - mx);
      acc[t][r] = e;
      sm += e;
    }
  }
  sm += __shfl_xor(sm, 16);
  sm += __shfl_xor(sm, 32);
  if (kq == 0) reds[w * 16 + lr] = sm;
  __syncthreads();  // barrier B
  float smt = reds[lr];
#pragma unroll
  for (int ww = 1; ww < 8; ++ww) smt += reds[ww * 16 + lr];
  float inv = 1.0f / smt;

  // --- write attn f32 + P bf16 into U (K staging done; swizzled chunks) ----
  float* arow = attn + (((size_t)z * 2048 + q0 + lr) * 2048);
#pragma unroll
  for (int t = 0; t < 16; ++t) {
    int key = t * 128 + w * 16 + kq * 4;
    f32x4 p = acc[t] * inv;
    *(f32x4*)(arow + key) = p;
    bf16x4 pb;
#pragma unroll
    for (int r = 0; r < 4; ++r) pb[r] = (short)f2bf(p[r]);
    int c8 = key >> 3;  // 16B chunk index in q-row
    *(bf16x4*)(U + lr * 4096 + ((c8 ^ (lr & 7)) << 4) + ((key & 7) << 1)) = pb;
  }
  __syncthreads();  // barrier C: P ready, red reads done, stores drained

  // --- PV: wave-private V staging, counted-vmcnt pipeline ------------------
  const unsigned short* Bv = vT + (size_t)gz * 524288 + bz * 2048;
  const int d0 = w * 16;
  const int vd = lane >> 2;                 // 0..15 local d-row
  const int vcs = (lane & 3) ^ (vd & 3);    // pre-swizzled source chunk
  auto stageV = [&](int buf, int t) {
    ASYNC16(Vb + buf * 8192 + w * 1024 + lane * 16,
            Bv + (size_t)(d0 + vd) * 4096 + t * 32 + vcs * 8);
  };

  f32x4 cfr = {};
  stageV(0, 0);
  stageV(1, 1);
#pragma unroll
  for (int t = 0; t < 64; ++t) {
    if (t < 63) asm volatile("s_waitcnt vmcnt(1)" ::: "memory");
    else        asm volatile("s_waitcnt vmcnt(0)" ::: "memory");
    __builtin_amdgcn_sched_barrier(0);
    int c8 = t * 4 + kq;
    bf16x8 pfr = *(const bf16x8*)(U + lr * 4096 + ((c8 ^ (lr & 7)) << 4));
    const char* Vw = Vb + (t & 1) * 8192 + w * 1024;
    bf16x8 vfr = *(const bf16x8*)(Vw + lr * 64 + ((kq ^ (lr & 3)) << 4));
    asm volatile("s_waitcnt lgkmcnt(0)" ::: "memory");
    __builtin_amdgcn_sched_barrier(0);
    if (t + 2 < 64) stageV(t & 1, t + 2);  // reuse just-read buffer
    cfr = __builtin_amdgcn_mfma_f32_16x16x32_bf16(pfr, vfr, cfr, 0, 0, 0);
  }
#pragma unroll
  for (int r = 0; r < 4; ++r) {
    int q = kq * 4 + r;
    ctx[((size_t)(bz * 2048 + q0 + q) * 2048) + hz * 128 + d0 + lr] =
        f2bf(cfr[r]);
  }
}

// ===========================================================================
// 256x128 8-wave double-buffered GEMM, BK=64 (front-loaded gll16 + swizzle)
// ===========================================================================
template <bool OUT_BF16>
__global__ __launch_bounds__(512, 2) void gemm256(
    const unsigned short* __restrict__ A, const unsigned short* __restrict__ Bt,
    void* __restrict__ C_, int K, int lda, int ldb, int ldc) {
  __shared__ unsigned short As[2][256 * 64];  // 64 KB
  __shared__ unsigned short Bs[2][128 * 64];  // 32 KB
  const int tid = threadIdx.x;
  const int bm0 = blockIdx.y * 256, bn0 = blockIdx.x * 128;
  const int lane = tid & 63, wid = tid >> 6;
  const int wr = wid >> 2, wc = wid & 3;
  const int lr = lane & 15, kq = lane >> 4;

  f32x4 acc[8][2] = {};

  int sArow[4], sAcc[4], sBrow[2], sBcc[2];
#pragma unroll
  for (int R = 0; R < 4; ++R) {
    int c = R * 512 + tid;
    sArow[R] = c >> 3;
    sAcc[R]  = (c & 7) ^ (sArow[R] & 7);
  }
#pragma unroll
  for (int R = 0; R < 2; ++R) {
    int c = R * 512 + tid;
    sBrow[R] = c >> 3;
    sBcc[R]  = (c & 7) ^ (sBrow[R] & 7);
  }

  auto stage = [&](int buf, int k0) {
#pragma unroll
    for (int R = 0; R < 4; ++R)
      ASYNC16(&As[buf][(R * 512 + tid) * 8],
              A + (size_t)(bm0 + sArow[R]) * lda + k0 + sAcc[R] * 8);
#pragma unroll
    for (int R = 0; R < 2; ++R)
      ASYNC16(&Bs[buf][(R * 512 + tid) * 8],
              Bt + (size_t)(bn0 + sBrow[R]) * ldb + k0 + sBcc[R] * 8);
  };

  const int NT = K >> 6;
  stage(0, 0);
  __syncthreads();
  int cur = 0;
  for (int t = 0; t < NT; ++t) {
    if (t + 1 < NT) stage(cur ^ 1, (t + 1) << 6);
    const unsigned short* Ac = As[cur];
    const unsigned short* Bc = Bs[cur];
    __builtin_amdgcn_s_setprio(1);
#pragma unroll
    for (int ks = 0; ks < 2; ++ks) {
      bf16x8 afr[8];
#pragma unroll
      for (int i = 0; i < 8; ++i) {
        int row = wr * 128 + i * 16 + lr;
        int cch = (ks * 4 + kq) ^ (row & 7);
        afr[i] = *(const bf16x8*)&Ac[(row * 8 + cch) * 8];
      }
#pragma unroll
      for (int j = 0; j < 2; ++j) {
        int brow = wc * 32 + j * 16 + lr;
        int cch = (ks * 4 + kq) ^ (brow & 7);
        bf16x8 bfr = *(const bf16x8*)&Bc[(brow * 8 + cch) * 8];
#pragma unroll
        for (int i = 0; i < 8; ++i)
          acc[i][j] = __builtin_amdgcn_mfma_f32_16x16x32_bf16(afr[i], bfr,
                                                              acc[i][j], 0, 0, 0);
      }
    }
    __builtin_amdgcn_s_setprio(0);
    __syncthreads();
    cur ^= 1;
  }

#pragma unroll
  for (int i = 0; i < 8; ++i)
#pragma unroll
    for (int j = 0; j < 2; ++j) {
      int rowb = bm0 + wr * 128 + i * 16 + kq * 4;
      int col = bn0 + wc * 32 + j * 16 + lr;
#pragma unroll
      for (int r = 0; r < 4; ++r) {
        if constexpr (OUT_BF16)
          ((unsigned short*)C_)[(size_t)(rowb + r) * ldc + col] = f2bf(acc[i][j][r]);
        else
          ((float*)C_)[(size_t)(rowb + r) * ldc + col] = acc[i][j][r];
      }
    }
}

// ---- same structure, dual-B GeGLU: h = (A@B1^T) * gelu(A@B2^T) -------------
__global__ __launch_bounds__(512, 2) void gemm_geglu256(
    const unsigned short* __restrict__ A, const unsigned short* __restrict__ B1,
    const unsigned short* __restrict__ B2, unsigned short* __restrict__ H_,
    int K, int lda, int ldb, int ldc) {
  __shared__ unsigned short As[2][256 * 64];   // 64 KB
  __shared__ unsigned short B1s[2][128 * 64];  // 32 KB
  __shared__ unsigned short B2s[2][128 * 64];  // 32 KB
  const int tid = threadIdx.x;
  const int bm0 = blockIdx.y * 256, bn0 = blockIdx.x * 128;
  const int lane = tid & 63, wid = tid >> 6;
  const int wr = wid >> 2, wc = wid & 3;
  const int lr = lane & 15, kq = lane >> 4;

  f32x4 accu[8][2] = {};
  f32x4 accg[8][2] = {};

  int sArow[4], sAcc[4], sBrow[2], sBcc[2];
#pragma unroll
  for (int R = 0; R < 4; ++R) {
    int c = R * 512 + tid;
    sArow[R] = c >> 3;
    sAcc[R]  = (c & 7) ^ (sArow[R] & 7);
  }
#pragma unroll
  for (int R = 0; R < 2; ++R) {
    int c = R * 512 + tid;
    sBrow[R] = c >> 3;
    sBcc[R]  = (c & 7) ^ (sBrow[R] & 7);
  }

  auto stage = [&](int buf, int k0) {
#pragma unroll
    for (int R = 0; R < 4; ++R)
      ASYNC16(&As[buf][(R * 512 + tid) * 8],
              A + (size_t)(bm0 + sArow[R]) * lda + k0 + sAcc[R] * 8);
#pragma unroll
    for (int R = 0; R < 2; ++R)
      ASYNC16(&B1s[buf][(R * 512 + tid) * 8],
              B1 + (size_t)(bn0 + sBrow[R]) * ldb + k0 + sBcc[R] * 8);
#pragma unroll
    for (int R = 0; R < 2; ++R)
      ASYNC16(&B2s[buf][(R * 512 + tid) * 8],
              B2 + (size_t)(bn0 + sBrow[R]) * ldb + k0 + sBcc[R] * 8);
  };

  const int NT = K >> 6;
  stage(0, 0);
  __syncthreads();
  int cur = 0;
  for (int t = 0; t < NT; ++t) {
    if (t + 1 < NT) stage(cur ^ 1, (t + 1) << 6);
    const unsigned short* Ac = As[cur];
    const unsigned short* B1c = B1s[cur];
    const unsigned short* B2c = B2s[cur];
    __builtin_amdgcn_s_setprio(1);
#pragma unroll
    for (int ks = 0; ks < 2; ++ks) {
      bf16x8 afr[8];
#pragma unroll
      for (int i = 0; i < 8; ++i) {
        int row = wr * 128 + i * 16 + lr;
        int cch = (ks * 4 + kq) ^ (row & 7);
        afr[i] = *(const bf16x8*)&Ac[(row * 8 + cch) * 8];
      }
#pragma unroll
      for (int j = 0; j < 2; ++j) {
        int brow = wc * 32 + j * 16 + lr;
        int cch = (ks * 4 + kq) ^ (brow & 7);
        bf16x8 b1 = *(const bf16x8*)&B1c[(brow * 8 + cch) * 8];
        bf16x8 b2 = *(const bf16x8*)&B2c[(brow * 8 + cch) * 8];
#pragma unroll
        for (int i = 0; i < 8; ++i) {
          accu[i][j] = __builtin_amdgcn_mfma_f32_16x16x32_bf16(afr[i], b1,
                                                               accu[i][j], 0, 0, 0);
          accg[i][j] = __builtin_amdgcn_mfma_f32_16x16x32_bf16(afr[i], b2,
                                                               accg[i][j], 0, 0, 0);
        }
      }
    }
    __builtin_amdgcn_s_setprio(0);
    __syncthreads();
    cur ^= 1;
  }

#pragma unroll
  for (int i = 0; i < 8; ++i)
#pragma unroll
    for (int j = 0; j < 2; ++j) {
      int rowb = bm0 + wr * 128 + i * 16 + kq * 4;
      int col = bn0 + wc * 32 + j * 16 + lr;
#pragma unroll
      for (int r = 0; r < 4; ++r) {
        float u = accu[i][j][r];
        float g = accg[i][j][r];
        float tv = tanhf(0.7978845608028654f * (g + 0.044715f * g * g * g));
        float hv = u * 0.5f * g * (1.0f + tv);
        H_[(size_t)(rowb + r) * ldc + col] = f2bf(hv);
      }
    }
}

// ---------------------------------------------------------------------------
extern "C" void kernel_launch(void* const* d_in, const int* in_sizes, int n_in,
                              void* d_out, int out_size, void* d_ws, size_t ws_size,
                              hipStream_t stream) {
  const float* x   = (const float*)d_in[0];
  const float* wq  = (const float*)d_in[1];
  const float* wk  = (const float*)d_in[2];
  const float* wv  = (const float*)d_in[3];
  const float* wo  = (const float*)d_in[4];
  const float* w1  = (const float*)d_in[5];
  const float* w2  = (const float*)d_in[6];
  const float* n1w = (const float*)d_in[7];
  const float* n2w = (const float*)d_in[8];

  float* out    = (float*)d_out;
  float* x2_out = out;
  float* k_out  = out + 8388608;
  float* v_out  = out + 16777216;
  float* attn   = out + 25165824;  // 134,217,728 f32

  char* ws = (char*)d_ws;
  unsigned short* wqT  = (unsigned short*)(ws + 0);
  unsigned short* wkT  = (unsigned short*)(ws + 8388608);
  unsigned short* wvT  = (unsigned short*)(ws + 10485760);
  unsigned short* woT  = (unsigned short*)(ws + 12582912);
  unsigned short* w1T  = (unsigned short*)(ws + 20971520);
  unsigned short* w2T  = (unsigned short*)(ws + 88080384);
  unsigned short* qh   = (unsigned short*)(ws + 121634816);
  unsigned short* kh   = (unsigned short*)(ws + 138412032);
  unsigned short* vhT  = (unsigned short*)(ws + 142606336);
  unsigned short* ctx  = (unsigned short*)(ws + 146800640);
  float*          ao   = (float*)(ws + 163577856);
  unsigned short* hbuf = (unsigned short*)(ws + 121634816);  // alias qh..ao (dead)
  unsigned short* x1b  = (unsigned short*)(ws + 197132288);
  unsigned short* fc   = (unsigned short*)(ws + 213909504);
  // ws total: 230,686,720 bytes

  // bf16 scratch inside not-yet-written attn region of d_out
  unsigned short* xb = (unsigned short*)attn;   // bf16(x), 8,388,608 elems
  unsigned short* xq = xb + 8388608;            // bf16(rope(x))

  dim3 blk(256);
  dim3 blk512(512);

  // 1) weight convert+transpose (f32 [K,N] -> bf16 [N,K])
  kconvT<<<dim3(64, 64), blk, 0, stream>>>(wq, wqT, 2048, 2048);
  kconvT<<<dim3(16, 64), blk, 0, stream>>>(wk, wkT, 2048, 512);
  kconvT<<<dim3(16, 64), blk, 0, stream>>>(wv, wvT, 2048, 512);
  kconvT<<<dim3(64, 64), blk, 0, stream>>>(wo, woT, 2048, 2048);
  kconvT<<<dim3(512, 64), blk, 0, stream>>>(w1, w1T, 2048, 16384);
  kconvT<<<dim3(64, 256), blk, 0, stream>>>(w2, w2T, 8192, 2048);

  // 2) v_flat = x ; xb = bf16(x)
  kcopy<<<8192, blk, 0, stream>>>((const f32x4*)x, (f32x4*)v_out, (u16x4*)xb);
  // 3) k_flat = rope(x) f32 ; xq = bf16(rope(x))
  krope<<<16384, blk, 0, stream>>>(x, k_out, xq);

  // 4) projections
  gemm256<true><<<dim3(16, 16), blk512, 0, stream>>>(
      xq, wqT, qh, 2048, 2048, 2048, 2048);
  gemm_bt<true, false><<<dim3(4, 32), blk, 0, stream>>>(
      xq, wkT, kh, 2048, 2048, 2048, 512, 1.0f);
  gemm_bt<true, true><<<dim3(4, 32), blk, 0, stream>>>(
      xb, wvT, vhT, 2048, 2048, 2048, 4096, 1.0f);

  // 5) fused scores + softmax + attn write + PV -> ctx (XCD-swizzled 1D grid)
  kattn<<<dim3(4096), blk512, 0, stream>>>(qh, kh, vhT, attn, ctx);

  // 6) attn_out = ctx @ wo (f32)
  gemm256<false><<<dim3(16, 16), blk512, 0, stream>>>(
      ctx, woT, (void*)ao, 2048, 2048, 2048, 2048);
  // 7) x1b = rmsnorm(x + ao) * n1w
  krms1<<<4096, blk, 0, stream>>>(x, ao, n1w, x1b);
  // 8) h = u * gelu(gate)  (fused dual GEMM, uv never materialized)
  gemm_geglu256<<<dim3(64, 16), blk512, 0, stream>>>(
      x1b, w1T, w1T + 16777216, hbuf, 2048, 2048, 2048, 8192);
  // 9) fc = h @ w2
  gemm256<true><<<dim3(16, 16), blk512, 0, stream>>>(
      hbuf, w2T, fc, 8192, 8192, 8192, 2048);
  // 10) x2 = rmsnorm(x1 + fc) * n2w
  krms2<<<4096, blk, 0, stream>>>(x1b, fc, n2w, x2_out);
}

// Round 11
// 1059.107 us; speedup vs baseline: 1.3049x; 1.0519x over previous
//
#include <hip/hip_runtime.h>
#include <hip/hip_bf16.h>

// ---------------------------------------------------------------------------
// TransformerBlock: B=2 N=2048 E=2048 H=16 G=4 D=128 HID=8192
// out = [ x2 (8.39M f32) | k_flat (8.39M) | v_flat (8.39M) | attn (134.2M) ]
// R11: gemm256/gemm_geglu256 -> counted-vmcnt drain-free pipeline (T4):
//      raw s_barrier + vmcnt(6|8) (never 0 mid-loop), 2-tile prefetch,
//      stage after read-barrier, ks-split MFMA/read interleave.
//      R10 attribution: GEMM stack ~640us @ ~750TF (m97-class drain stall).
//      kattn v5 (XCD swizzle, confirmed +68us) unchanged.
// ---------------------------------------------------------------------------

using f32x4  = __attribute__((ext_vector_type(4))) float;
using bf16x8 = __attribute__((ext_vector_type(8))) short;
using bf16x4 = __attribute__((ext_vector_type(4))) short;
using u16x4  = __attribute__((ext_vector_type(4))) unsigned short;

#define DEV __device__ __forceinline__

// async global->LDS, 16B per lane; LDS dest must be wave-uniform base + lane*16
#define ASYNC16(lds, g)                                                        \
  __builtin_amdgcn_global_load_lds(                                           \
      (const __attribute__((address_space(1))) void*)(g),                      \
      (__attribute__((address_space(3))) void*)(lds), 16, 0, 0)

DEV unsigned short f2bf(float f) {
  unsigned int u = __float_as_uint(f);
  return (unsigned short)((u + 0x7fffu + ((u >> 16) & 1u)) >> 16);
}
DEV float bf2f(unsigned short h) {
  return __uint_as_float(((unsigned int)h) << 16);
}

DEV float waveRedSum(float v) {
#pragma unroll
  for (int o = 32; o; o >>= 1) v += __shfl_xor(v, o);
  return v;
}

// ---- transpose+convert: in f32 [K,N] -> out bf16 [N,K] ---------------------
__global__ __launch_bounds__(256) void kconvT(const float* __restrict__ in,
                                              unsigned short* __restrict__ out,
                                              int K, int N) {
  __shared__ float tile[32][33];
  int bx = blockIdx.x * 32;  // N dim
  int by = blockIdx.y * 32;  // K dim
  int tx = threadIdx.x & 31;
  int ty = threadIdx.x >> 5;  // 0..7
#pragma unroll
  for (int i = 0; i < 32; i += 8)
    tile[ty + i][tx] = in[(size_t)(by + ty + i) * N + bx + tx];
  __syncthreads();
#pragma unroll
  for (int i = 0; i < 32; i += 8)
    out[(size_t)(bx + ty + i) * K + by + tx] = f2bf(tile[tx][ty + i]);
}

// ---- v_flat = x (f32 copy) and x_bf16 --------------------------------------
__global__ __launch_bounds__(256) void kcopy(const f32x4* __restrict__ x,
                                             f32x4* __restrict__ v,
                                             u16x4* __restrict__ xb) {
  int i = blockIdx.x * 256 + threadIdx.x;  // exactly 2,097,152 threads
  f32x4 val = x[i];
  v[i] = val;
  u16x4 o;
  o[0] = f2bf(val[0]); o[1] = f2bf(val[1]); o[2] = f2bf(val[2]); o[3] = f2bf(val[3]);
  xb[i] = o;
}

// ---- RoPE on per-head slices of x -> k_flat f32 (d_out) + xq bf16 ----------
__global__ __launch_bounds__(256) void krope(const float* __restrict__ x,
                                             float* __restrict__ kout,
                                             unsigned short* __restrict__ xq) {
  int idx = blockIdx.x * 256 + threadIdx.x;  // B*N*H*64 = 4,194,304
  int f  = idx & 63;
  int h  = (idx >> 6) & 15;
  int bn = idx >> 10;          // b*2048+n
  int n  = bn & 2047;
  size_t base = (size_t)bn * 2048 + h * 128;
  float inv = exp2f((float)f * (-13.287712379549449f / 64.0f));
  float ang = (float)n * inv;
  float c = cosf(ang), s = sinf(ang);
  float a = x[base + f], b = x[base + f + 64];
  float k1 = a * c - b * s;
  float k2 = b * c + a * s;
  kout[base + f]      = k1;
  kout[base + f + 64] = k2;
  xq[base + f]      = f2bf(k1);
  xq[base + f + 64] = f2bf(k2);
}

// ---- x1b = bf16(rmsnorm(x + ao) * w) ---------------------------------------
__global__ __launch_bounds__(256) void krms1(const float* __restrict__ x,
                                             const float* __restrict__ ao,
                                             const float* __restrict__ w,
                                             unsigned short* __restrict__ x1b) {
  size_t row = blockIdx.x;
  const f32x4* xp = (const f32x4*)(x + row * 2048);
  const f32x4* ap = (const f32x4*)(ao + row * 2048);
  int tid = threadIdx.x;
  f32x4 t0 = xp[tid * 2] + ap[tid * 2];
  f32x4 t1 = xp[tid * 2 + 1] + ap[tid * 2 + 1];
  float ss = 0.f;
#pragma unroll
  for (int i = 0; i < 4; ++i) ss += t0[i] * t0[i] + t1[i] * t1[i];
  ss = waveRedSum(ss);
  __shared__ float red[4];
  int wid = tid >> 6, lane = tid & 63;
  if (!lane) red[wid] = ss;
  __syncthreads();
  ss = red[0] + red[1] + red[2] + red[3];
  float rr = rsqrtf(ss * (1.0f / 2048.0f) + 1e-6f);
  const f32x4* wp = (const f32x4*)w;
  f32x4 w0 = wp[tid * 2], w1 = wp[tid * 2 + 1];
  u16x4 o0, o1;
#pragma unroll
  for (int i = 0; i < 4; ++i) {
    o0[i] = f2bf(t0[i] * rr * w0[i]);
    o1[i] = f2bf(t1[i] * rr * w1[i]);
  }
  u16x4* op = (u16x4*)(x1b + row * 2048);
  op[tid * 2] = o0;
  op[tid * 2 + 1] = o1;
}

// ---- x2 = f32(rmsnorm(x1b + fc) * w) -> d_out ------------------------------
__global__ __launch_bounds__(256) void krms2(const unsigned short* __restrict__ x1b,
                                             const unsigned short* __restrict__ fc,
                                             const float* __restrict__ w,
                                             float* __restrict__ out) {
  size_t row = blockIdx.x;
  const u16x4* xp = (const u16x4*)(x1b + row * 2048);
  const u16x4* fp = (const u16x4*)(fc + row * 2048);
  int tid = threadIdx.x;
  u16x4 a0 = xp[tid * 2], a1 = xp[tid * 2 + 1];
  u16x4 b0 = fp[tid * 2], b1 = fp[tid * 2 + 1];
  f32x4 t0, t1;
#pragma unroll
  for (int i = 0; i < 4; ++i) {
    t0[i] = bf2f(a0[i]) + bf2f(b0[i]);
    t1[i] = bf2f(a1[i]) + bf2f(b1[i]);
  }
  float ss = 0.f;
#pragma unroll
  for (int i = 0; i < 4; ++i) ss += t0[i] * t0[i] + t1[i] * t1[i];
  ss = waveRedSum(ss);
  __shared__ float red[4];
  int wid = tid >> 6, lane = tid & 63;
  if (!lane) red[wid] = ss;
  __syncthreads();
  ss = red[0] + red[1] + red[2] + red[3];
  float rr = rsqrtf(ss * (1.0f / 2048.0f) + 1e-6f);
  const f32x4* wp = (const f32x4*)w;
  f32x4 w0 = wp[tid * 2], w1 = wp[tid * 2 + 1];
  f32x4* op = (f32x4*)(out + row * 2048);
  op[tid * 2]     = t0 * rr * w0;
  op[tid * 2 + 1] = t1 * rr * w1;
}

// ---- 128x128 MFMA GEMM (small shapes: k/v projections) ---------------------
template <bool OUT_BF16, bool TRANS_OUT>
__global__ __launch_bounds__(256, 2) void gemm_bt(
    const unsigned short* __restrict__ A, const unsigned short* __restrict__ Bt,
    void* __restrict__ C_, int K, int lda, int ldb, int ldc, float alpha) {
  __shared__ unsigned short As[128 * 32];
  __shared__ unsigned short Bs[128 * 32];
  const int tid = threadIdx.x;
  const int bm0 = blockIdx.y * 128, bn0 = blockIdx.x * 128;

  f32x4 acc[4][4] = {};

  const int lane = tid & 63, wid = tid >> 6;
  const int wr = wid >> 1, wc = wid & 1;
  const int lr = lane & 15, kq = lane >> 4;
  const int srow = tid >> 2;        // 0..63
  const int scol = (tid & 3) * 8;   // 0,8,16,24
  unsigned short* AsW = As + tid * 8;
  unsigned short* BsW = Bs + tid * 8;

  for (int kt = 0; kt < K; kt += 32) {
    ASYNC16(AsW,        A + (size_t)(bm0 + srow)      * lda + kt + scol);
    ASYNC16(AsW + 2048, A + (size_t)(bm0 + srow + 64) * lda + kt + scol);
    ASYNC16(BsW,        Bt + (size_t)(bn0 + srow)      * ldb + kt + scol);
    ASYNC16(BsW + 2048, Bt + (size_t)(bn0 + srow + 64) * ldb + kt + scol);
    __syncthreads();
    bf16x8 afr[4], bfr[4];
#pragma unroll
    for (int i = 0; i < 4; ++i)
      afr[i] = *(const bf16x8*)&As[(wr * 64 + i * 16 + lr) * 32 + kq * 8];
#pragma unroll
    for (int j = 0; j < 4; ++j)
      bfr[j] = *(const bf16x8*)&Bs[(wc * 64 + j * 16 + lr) * 32 + kq * 8];
#pragma unroll
    for (int i = 0; i < 4; ++i)
#pragma unroll
      for (int j = 0; j < 4; ++j)
        acc[i][j] = __builtin_amdgcn_mfma_f32_16x16x32_bf16(afr[i], bfr[j],
                                                            acc[i][j], 0, 0, 0);
    __syncthreads();
  }

#pragma unroll
  for (int i = 0; i < 4; ++i)
#pragma unroll
    for (int j = 0; j < 4; ++j) {
      int rowb = bm0 + wr * 64 + i * 16 + kq * 4;
      int col = bn0 + wc * 64 + j * 16 + lr;
#pragma unroll
      for (int r = 0; r < 4; ++r) {
        float v = acc[i][j][r] * alpha;
        size_t idx = TRANS_OUT ? ((size_t)col * ldc + (rowb + r))
                               : ((size_t)(rowb + r) * ldc + col);
        if constexpr (OUT_BF16)
          ((unsigned short*)C_)[idx] = f2bf(v);
        else
          ((float*)C_)[idx] = v;
      }
    }
}

// ===========================================================================
// Fused attention v5 (unchanged from R10): v4 counted-vmcnt pipeline +
// XCD-locality block swizzle (g8 = bid&7 pins each (b,g) slice to one XCD).
// ===========================================================================
__global__ __launch_bounds__(512, 4) void kattn(
    const unsigned short* __restrict__ qh,   // [b][n][h*128+d] ld 2048
    const unsigned short* __restrict__ kh,   // [b][n][g*128+d] ld 512
    const unsigned short* __restrict__ vT,   // [g*128+d][b*2048+key] ld 4096
    float* __restrict__ attn,                // [b][h][q][key]
    unsigned short* __restrict__ ctx) {      // [b][n][h*128+d] ld 2048
  __shared__ __align__(16) char U[65536];
  __shared__ __align__(16) char Vb[16384];
  float* redm = (float*)Vb;         // [8][16]
  float* reds = redm + 128;         // [8][16]

  const int tid = threadIdx.x;
  const int lane = tid & 63, w = tid >> 6;   // w 0..7
  const int lr = lane & 15, kq = lane >> 4;  // q = lr, quarter = kq
  const int bid = blockIdx.x;
  const int g8 = bid & 7;          // (b,g) slice, 0..7
  const int j  = bid >> 3;         // 0..511
  const int bz = g8 >> 2;          // batch
  const int gz = g8 & 3;           // kv group
  const int hz = gz * 4 + (j & 3); // head (hz>>2 == gz)
  const int q0 = (j >> 2) << 4;    // q-tile * 16
  const int z  = bz * 16 + hz;

  const unsigned short* Aq =
      qh + ((size_t)(bz * 2048 + q0 + lr) * 2048 + hz * 128);
  bf16x8 qfr[4];
#pragma unroll
  for (int kk = 0; kk < 4; ++kk)
    qfr[kk] = *(const bf16x8*)(Aq + kk * 32 + kq * 8);

  const unsigned short* Kb =
      kh + ((size_t)(bz * 2048) * 512 + gz * 128);
  int krow[4], kcs[4];
#pragma unroll
  for (int R = 0; R < 4; ++R) {
    int idx = R * 64 + lane;
    krow[R] = idx >> 4;
    kcs[R] = (idx & 15) ^ (krow[R] & 7);  // pre-swizzled source chunk
  }
  auto stageK = [&](int buf, int t) {
#pragma unroll
    for (int R = 0; R < 4; ++R)
      ASYNC16(U + buf * 32768 + w * 4096 + (R * 64 + lane) * 16,
              Kb + (size_t)(t * 128 + w * 16 + krow[R]) * 512 + kcs[R] * 8);
  };

  f32x4 acc[16];
#pragma unroll
  for (int t = 0; t < 16; ++t) acc[t] = f32x4{0.f, 0.f, 0.f, 0.f};

  stageK(0, 0);
  stageK(1, 1);
#pragma unroll
  for (int t = 0; t < 16; ++t) {
    if (t < 15) asm volatile("s_waitcnt vmcnt(4)" ::: "memory");
    else        asm volatile("s_waitcnt vmcnt(0)" ::: "memory");
    __builtin_amdgcn_sched_barrier(0);
    const char* Kw = U + (t & 1) * 32768 + w * 4096;
    bf16x8 kfr[4];
#pragma unroll
    for (int kk = 0; kk < 4; ++kk) {
      int cch = (kk * 4 + kq) ^ (lr & 7);
      kfr[kk] = *(const bf16x8*)(Kw + lr * 256 + cch * 16);
    }
    asm volatile("s_waitcnt lgkmcnt(0)" ::: "memory");
    __builtin_amdgcn_sched_barrier(0);
    if (t + 2 < 16) stageK(t & 1, t + 2);  // reuse just-read buffer
#pragma unroll
    for (int kk = 0; kk < 4; ++kk)
      acc[t] = __builtin_amdgcn_mfma_f32_16x16x32_bf16(kfr[kk], qfr[kk],
                                                       acc[t], 0, 0, 0);
  }

  const float scale = 0.08838834764831845f;
  float mx = -3.4e38f;
#pragma unroll
  for (int t = 0; t < 16; ++t) {
    acc[t] *= scale;
#pragma unroll
    for (int r = 0; r < 4; ++r) mx = fmaxf(mx, acc[t][r]);
  }
  mx = fmaxf(mx, __shfl_xor(mx, 16));
  mx = fmaxf(mx, __shfl_xor(mx, 32));
  if (kq == 0) redm[w * 16 + lr] = mx;
  __syncthreads();  // barrier A
  mx = redm[lr];
#pragma unroll
  for (int ww = 1; ww < 8; ++ww) mx = fmaxf(mx, redm[ww * 16 + lr]);

  float sm = 0.f;
#pragma unroll
  for (int t = 0; t < 16; ++t) {
#pragma unroll
    for (int r = 0; r < 4; ++r) {
      float e = __expf(acc[t][r] - mx);
      acc[t][r] = e;
      sm += e;
    }
  }
  sm += __shfl_xor(sm, 16);
  sm += __shfl_xor(sm, 32);
  if (kq == 0) reds[w * 16 + lr] = sm;
  __syncthreads();  // barrier B
  float smt = reds[lr];
#pragma unroll
  for (int ww = 1; ww < 8; ++ww) smt += reds[ww * 16 + lr];
  float inv = 1.0f / smt;

  float* arow = attn + (((size_t)z * 2048 + q0 + lr) * 2048);
#pragma unroll
  for (int t = 0; t < 16; ++t) {
    int key = t * 128 + w * 16 + kq * 4;
    f32x4 p = acc[t] * inv;
    *(f32x4*)(arow + key) = p;
    bf16x4 pb;
#pragma unroll
    for (int r = 0; r < 4; ++r) pb[r] = (short)f2bf(p[r]);
    int c8 = key >> 3;  // 16B chunk index in q-row
    *(bf16x4*)(U + lr * 4096 + ((c8 ^ (lr & 7)) << 4) + ((key & 7) << 1)) = pb;
  }
  __syncthreads();  // barrier C: P ready, red reads done, stores drained

  const unsigned short* Bv = vT + (size_t)gz * 524288 + bz * 2048;
  const int d0 = w * 16;
  const int vd = lane >> 2;                 // 0..15 local d-row
  const int vcs = (lane & 3) ^ (vd & 3);    // pre-swizzled source chunk
  auto stageV = [&](int buf, int t) {
    ASYNC16(Vb + buf * 8192 + w * 1024 + lane * 16,
            Bv + (size_t)(d0 + vd) * 4096 + t * 32 + vcs * 8);
  };

  f32x4 cfr = {};
  stageV(0, 0);
  stageV(1, 1);
#pragma unroll
  for (int t = 0; t < 64; ++t) {
    if (t < 63) asm volatile("s_waitcnt vmcnt(1)" ::: "memory");
    else        asm volatile("s_waitcnt vmcnt(0)" ::: "memory");
    __builtin_amdgcn_sched_barrier(0);
    int c8 = t * 4 + kq;
    bf16x8 pfr = *(const bf16x8*)(U + lr * 4096 + ((c8 ^ (lr & 7)) << 4));
    const char* Vw = Vb + (t & 1) * 8192 + w * 1024;
    bf16x8 vfr = *(const bf16x8*)(Vw + lr * 64 + ((kq ^ (lr & 3)) << 4));
    asm volatile("s_waitcnt lgkmcnt(0)" ::: "memory");
    __builtin_amdgcn_sched_barrier(0);
    if (t + 2 < 64) stageV(t & 1, t + 2);  // reuse just-read buffer
    cfr = __builtin_amdgcn_mfma_f32_16x16x32_bf16(pfr, vfr, cfr, 0, 0, 0);
  }
#pragma unroll
  for (int r = 0; r < 4; ++r) {
    int q = kq * 4 + r;
    ctx[((size_t)(bz * 2048 + q0 + q) * 2048) + hz * 128 + d0 + lr] =
        f2bf(cfr[r]);
  }
}

// ===========================================================================
// 256x128 8-wave GEMM, BK=64 — counted-vmcnt drain-free pipeline (R11).
// Ledger: stage(t) issued at iter t-2 (prologue: t=0,1). At iter t top,
// outstanding = tile t+1's 6 loads (newest) [+ tile t's if slow, older] ->
// vmcnt(6) guarantees tile t resident (vmcnt(0) peeled on last iter).
// barrier1 aligns all waves; ks0 reads+MFMA; ks1 reads; lgkmcnt(0)+barrier2
// -> all waves' reads of buf[cur] done -> stage tile t+2 into buf[cur];
// MFMA ks1 overlaps the staging. No vmcnt(0) drain mid-loop.
// ===========================================================================
template <bool OUT_BF16>
__global__ __launch_bounds__(512, 2) void gemm256(
    const unsigned short* __restrict__ A, const unsigned short* __restrict__ Bt,
    void* __restrict__ C_, int K, int lda, int ldb, int ldc) {
  __shared__ unsigned short As[2][256 * 64];  // 64 KB
  __shared__ unsigned short Bs[2][128 * 64];  // 32 KB
  const int tid = threadIdx.x;
  const int bm0 = blockIdx.y * 256, bn0 = blockIdx.x * 128;
  const int lane = tid & 63, wid = tid >> 6;
  const int wr = wid >> 2, wc = wid & 3;
  const int lr = lane & 15, kq = lane >> 4;

  f32x4 acc[8][2] = {};

  int sArow[4], sAcc[4], sBrow[2], sBcc[2];
#pragma unroll
  for (int R = 0; R < 4; ++R) {
    int c = R * 512 + tid;
    sArow[R] = c >> 3;
    sAcc[R]  = (c & 7) ^ (sArow[R] & 7);
  }
#pragma unroll
  for (int R = 0; R < 2; ++R) {
    int c = R * 512 + tid;
    sBrow[R] = c >> 3;
    sBcc[R]  = (c & 7) ^ (sBrow[R] & 7);
  }

  auto stage = [&](int buf, int k0) {  // 6 loads/thread
#pragma unroll
    for (int R = 0; R < 4; ++R)
      ASYNC16(&As[buf][(R * 512 + tid) * 8],
              A + (size_t)(bm0 + sArow[R]) * lda + k0 + sAcc[R] * 8);
#pragma unroll
    for (int R = 0; R < 2; ++R)
      ASYNC16(&Bs[buf][(R * 512 + tid) * 8],
              Bt + (size_t)(bn0 + sBrow[R]) * ldb + k0 + sBcc[R] * 8);
  };

  const int NT = K >> 6;
  stage(0, 0);
  stage(1, 64);
  int cur = 0;
  for (int t = 0; t < NT; ++t) {
    if (t + 1 < NT) asm volatile("s_waitcnt vmcnt(6)" ::: "memory");
    else            asm volatile("s_waitcnt vmcnt(0)" ::: "memory");
    __builtin_amdgcn_sched_barrier(0);
    __builtin_amdgcn_s_barrier();
    __builtin_amdgcn_sched_barrier(0);
    const unsigned short* Ac = As[cur];
    const unsigned short* Bc = Bs[cur];
    // ---- ks = 0: reads + 16 MFMA (compiler inserts lgkm waits) ----
    bf16x8 afr0[8], bfr0[2];
#pragma unroll
    for (int i = 0; i < 8; ++i) {
      int row = wr * 128 + i * 16 + lr;
      afr0[i] = *(const bf16x8*)&Ac[(row * 8 + (kq ^ (row & 7))) * 8];
    }
#pragma unroll
    for (int j2 = 0; j2 < 2; ++j2) {
      int brow = wc * 32 + j2 * 16 + lr;
      bfr0[j2] = *(const bf16x8*)&Bc[(brow * 8 + (kq ^ (brow & 7))) * 8];
    }
    __builtin_amdgcn_s_setprio(1);
#pragma unroll
    for (int j2 = 0; j2 < 2; ++j2)
#pragma unroll
      for (int i = 0; i < 8; ++i)
        acc[i][j2] = __builtin_amdgcn_mfma_f32_16x16x32_bf16(afr0[i], bfr0[j2],
                                                             acc[i][j2], 0, 0, 0);
    __builtin_amdgcn_s_setprio(0);
    // ---- ks = 1: reads, then publish read-completion, then stage ----
    bf16x8 afr1[8], bfr1[2];
#pragma unroll
    for (int i = 0; i < 8; ++i) {
      int row = wr * 128 + i * 16 + lr;
      afr1[i] = *(const bf16x8*)&Ac[(row * 8 + ((4 + kq) ^ (row & 7))) * 8];
    }
#pragma unroll
    for (int j2 = 0; j2 < 2; ++j2) {
      int brow = wc * 32 + j2 * 16 + lr;
      bfr1[j2] = *(const bf16x8*)&Bc[(brow * 8 + ((4 + kq) ^ (brow & 7))) * 8];
    }
    asm volatile("s_waitcnt lgkmcnt(0)" ::: "memory");
    __builtin_amdgcn_sched_barrier(0);
    __builtin_amdgcn_s_barrier();   // all waves' reads of buf[cur] done
    __builtin_amdgcn_sched_barrier(0);
    if (t + 2 < NT) stage(cur, (t + 2) << 6);
    __builtin_amdgcn_s_setprio(1);
#pragma unroll
    for (int j2 = 0; j2 < 2; ++j2)
#pragma unroll
      for (int i = 0; i < 8; ++i)
        acc[i][j2] = __builtin_amdgcn_mfma_f32_16x16x32_bf16(afr1[i], bfr1[j2],
                                                             acc[i][j2], 0, 0, 0);
    __builtin_amdgcn_s_setprio(0);
    cur ^= 1;
  }

#pragma unroll
  for (int i = 0; i < 8; ++i)
#pragma unroll
    for (int j = 0; j < 2; ++j) {
      int rowb = bm0 + wr * 128 + i * 16 + kq * 4;
      int col = bn0 + wc * 32 + j * 16 + lr;
#pragma unroll
      for (int r = 0; r < 4; ++r) {
        if constexpr (OUT_BF16)
          ((unsigned short*)C_)[(size_t)(rowb + r) * ldc + col] = f2bf(acc[i][j][r]);
        else
          ((float*)C_)[(size_t)(rowb + r) * ldc + col] = acc[i][j][r];
      }
    }
}

// ---- same pipeline, dual-B GeGLU: h = (A@B1^T) * gelu(A@B2^T) --------------
__global__ __launch_bounds__(512, 2) void gemm_geglu256(
    const unsigned short* __restrict__ A, const unsigned short* __restrict__ B1,
    const unsigned short* __restrict__ B2, unsigned short* __restrict__ H_,
    int K, int lda, int ldb, int ldc) {
  __shared__ unsigned short As[2][256 * 64];   // 64 KB
  __shared__ unsigned short B1s[2][128 * 64];  // 32 KB
  __shared__ unsigned short B2s[2][128 * 64];  // 32 KB
  const int tid = threadIdx.x;
  const int bm0 = blockIdx.y * 256, bn0 = blockIdx.x * 128;
  const int lane = tid & 63, wid = tid >> 6;
  const int wr = wid >> 2, wc = wid & 3;
  const int lr = lane & 15, kq = lane >> 4;

  f32x4 accu[8][2] = {};
  f32x4 accg[8][2] = {};

  int sArow[4], sAcc[4], sBrow[2], sBcc[2];
#pragma unroll
  for (int R = 0; R < 4; ++R) {
    int c = R * 512 + tid;
    sArow[R] = c >> 3;
    sAcc[R]  = (c & 7) ^ (sArow[R] & 7);
  }
#pragma unroll
  for (int R = 0; R < 2; ++R) {
    int c = R * 512 + tid;
    sBrow[R] = c >> 3;
    sBcc[R]  = (c & 7) ^ (sBrow[R] & 7);
  }

  auto stage = [&](int buf, int k0) {  // 8 loads/thread
#pragma unroll
    for (int R = 0; R < 4; ++R)
      ASYNC16(&As[buf][(R * 512 + tid) * 8],
              A + (size_t)(bm0 + sArow[R]) * lda + k0 + sAcc[R] * 8);
#pragma unroll
    for (int R = 0; R < 2; ++R)
      ASYNC16(&B1s[buf][(R * 512 + tid) * 8],
              B1 + (size_t)(bn0 + sBrow[R]) * ldb + k0 + sBcc[R] * 8);
#pragma unroll
    for (int R = 0; R < 2; ++R)
      ASYNC16(&B2s[buf][(R * 512 + tid) * 8],
              B2 + (size_t)(bn0 + sBrow[R]) * ldb + k0 + sBcc[R] * 8);
  };

  const int NT = K >> 6;
  stage(0, 0);
  stage(1, 64);
  int cur = 0;
  for (int t = 0; t < NT; ++t) {
    if (t + 1 < NT) asm volatile("s_waitcnt vmcnt(8)" ::: "memory");
    else            asm volatile("s_waitcnt vmcnt(0)" ::: "memory");
    __builtin_amdgcn_sched_barrier(0);
    __builtin_amdgcn_s_barrier();
    __builtin_amdgcn_sched_barrier(0);
    const unsigned short* Ac = As[cur];
    const unsigned short* B1c = B1s[cur];
    const unsigned short* B2c = B2s[cur];
    // ---- ks = 0 ----
    bf16x8 afr0[8], b10[2], b20[2];
#pragma unroll
    for (int i = 0; i < 8; ++i) {
      int row = wr * 128 + i * 16 + lr;
      afr0[i] = *(const bf16x8*)&Ac[(row * 8 + (kq ^ (row & 7))) * 8];
    }
#pragma unroll
    for (int j2 = 0; j2 < 2; ++j2) {
      int brow = wc * 32 + j2 * 16 + lr;
      b10[j2] = *(const bf16x8*)&B1c[(brow * 8 + (kq ^ (brow & 7))) * 8];
      b20[j2] = *(const bf16x8*)&B2c[(brow * 8 + (kq ^ (brow & 7))) * 8];
    }
    __builtin_amdgcn_s_setprio(1);
#pragma unroll
    for (int j2 = 0; j2 < 2; ++j2)
#pragma unroll
      for (int i = 0; i < 8; ++i) {
        accu[i][j2] = __builtin_amdgcn_mfma_f32_16x16x32_bf16(afr0[i], b10[j2],
                                                              accu[i][j2], 0, 0, 0);
        accg[i][j2] = __builtin_amdgcn_mfma_f32_16x16x32_bf16(afr0[i], b20[j2],
                                                              accg[i][j2], 0, 0, 0);
      }
    __builtin_amdgcn_s_setprio(0);
    // ---- ks = 1 ----
    bf16x8 afr1[8], b11[2], b21[2];
#pragma unroll
    for (int i = 0; i < 8; ++i) {
      int row = wr * 128 + i * 16 + lr;
      afr1[i] = *(const bf16x8*)&Ac[(row * 8 + ((4 + kq) ^ (row & 7))) * 8];
    }
#pragma unroll
    for (int j2 = 0; j2 < 2; ++j2) {
      int brow = wc * 32 + j2 * 16 + lr;
      b11[j2] = *(const bf16x8*)&B1c[(brow * 8 + ((4 + kq) ^ (brow & 7))) * 8];
      b21[j2] = *(const bf16x8*)&B2c[(brow * 8 + ((4 + kq) ^ (brow & 7))) * 8];
    }
    asm volatile("s_waitcnt lgkmcnt(0)" ::: "memory");
    __builtin_amdgcn_sched_barrier(0);
    __builtin_amdgcn_s_barrier();
    __builtin_amdgcn_sched_barrier(0);
    if (t + 2 < NT) stage(cur, (t + 2) << 6);
    __builtin_amdgcn_s_setprio(1);
#pragma unroll
    for (int j2 = 0; j2 < 2; ++j2)
#pragma unroll
      for (int i = 0; i < 8; ++i) {
        accu[i][j2] = __builtin_amdgcn_mfma_f32_16x16x32_bf16(afr1[i], b11[j2],
                                                              accu[i][j2], 0, 0, 0);
        accg[i][j2] = __builtin_amdgcn_mfma_f32_16x16x32_bf16(afr1[i], b21[j2],
                                                              accg[i][j2], 0, 0, 0);
      }
    __builtin_amdgcn_s_setprio(0);
    cur ^= 1;
  }

#pragma unroll
  for (int i = 0; i < 8; ++i)
#pragma unroll
    for (int j = 0; j < 2; ++j) {
      int rowb = bm0 + wr * 128 + i * 16 + kq * 4;
      int col = bn0 + wc * 32 + j * 16 + lr;
#pragma unroll
      for (int r = 0; r < 4; ++r) {
        float u = accu[i][j][r];
        float g = accg[i][j][r];
        float tv = tanhf(0.7978845608028654f * (g + 0.044715f * g * g * g));
        float hv = u * 0.5f * g * (1.0f + tv);
        H_[(size_t)(rowb + r) * ldc + col] = f2bf(hv);
      }
    }
}

// ---------------------------------------------------------------------------
extern "C" void kernel_launch(void* const* d_in, const int* in_sizes, int n_in,
                              void* d_out, int out_size, void* d_ws, size_t ws_size,
                              hipStream_t stream) {
  const float* x   = (const float*)d_in[0];
  const float* wq  = (const float*)d_in[1];
  const float* wk  = (const float*)d_in[2];
  const float* wv  = (const float*)d_in[3];
  const float* wo  = (const float*)d_in[4];
  const float* w1  = (const float*)d_in[5];
  const float* w2  = (const float*)d_in[6];
  const float* n1w = (const float*)d_in[7];
  const float* n2w = (const float*)d_in[8];

  float* out    = (float*)d_out;
  float* x2_out = out;
  float* k_out  = out + 8388608;
  float* v_out  = out + 16777216;
  float* attn   = out + 25165824;  // 134,217,728 f32

  char* ws = (char*)d_ws;
  unsigned short* wqT  = (unsigned short*)(ws + 0);
  unsigned short* wkT  = (unsigned short*)(ws + 8388608);
  unsigned short* wvT  = (unsigned short*)(ws + 10485760);
  unsigned short* woT  = (unsigned short*)(ws + 12582912);
  unsigned short* w1T  = (unsigned short*)(ws + 20971520);
  unsigned short* w2T  = (unsigned short*)(ws + 88080384);
  unsigned short* qh   = (unsigned short*)(ws + 121634816);
  unsigned short* kh   = (unsigned short*)(ws + 138412032);
  unsigned short* vhT  = (unsigned short*)(ws + 142606336);
  unsigned short* ctx  = (unsigned short*)(ws + 146800640);
  float*          ao   = (float*)(ws + 163577856);
  unsigned short* hbuf = (unsigned short*)(ws + 121634816);  // alias qh..ao (dead)
  unsigned short* x1b  = (unsigned short*)(ws + 197132288);
  unsigned short* fc   = (unsigned short*)(ws + 213909504);
  // ws total: 230,686,720 bytes

  // bf16 scratch inside not-yet-written attn region of d_out
  unsigned short* xb = (unsigned short*)attn;   // bf16(x), 8,388,608 elems
  unsigned short* xq = xb + 8388608;            // bf16(rope(x))

  dim3 blk(256);
  dim3 blk512(512);

  // 1) weight convert+transpose (f32 [K,N] -> bf16 [N,K])
  kconvT<<<dim3(64, 64), blk, 0, stream>>>(wq, wqT, 2048, 2048);
  kconvT<<<dim3(16, 64), blk, 0, stream>>>(wk, wkT, 2048, 512);
  kconvT<<<dim3(16, 64), blk, 0, stream>>>(wv, wvT, 2048, 512);
  kconvT<<<dim3(64, 64), blk, 0, stream>>>(wo, woT, 2048, 2048);
  kconvT<<<dim3(512, 64), blk, 0, stream>>>(w1, w1T, 2048, 16384);
  kconvT<<<dim3(64, 256), blk, 0, stream>>>(w2, w2T, 8192, 2048);

  // 2) v_flat = x ; xb = bf16(x)
  kcopy<<<8192, blk, 0, stream>>>((const f32x4*)x, (f32x4*)v_out, (u16x4*)xb);
  // 3) k_flat = rope(x) f32 ; xq = bf16(rope(x))
  krope<<<16384, blk, 0, stream>>>(x, k_out, xq);

  // 4) projections
  gemm256<true><<<dim3(16, 16), blk512, 0, stream>>>(
      xq, wqT, qh, 2048, 2048, 2048, 2048);
  gemm_bt<true, false><<<dim3(4, 32), blk, 0, stream>>>(
      xq, wkT, kh, 2048, 2048, 2048, 512, 1.0f);
  gemm_bt<true, true><<<dim3(4, 32), blk, 0, stream>>>(
      xb, wvT, vhT, 2048, 2048, 2048, 4096, 1.0f);

  // 5) fused scores + softmax + attn write + PV -> ctx (XCD-swizzled 1D grid)
  kattn<<<dim3(4096), blk512, 0, stream>>>(qh, kh, vhT, attn, ctx);

  // 6) attn_out = ctx @ wo (f32)
  gemm256<false><<<dim3(16, 16), blk512, 0, stream>>>(
      ctx, woT, (void*)ao, 2048, 2048, 2048, 2048);
  // 7) x1b = rmsnorm(x + ao) * n1w
  krms1<<<4096, blk, 0, stream>>>(x, ao, n1w, x1b);
  // 8) h = u * gelu(gate)  (fused dual GEMM, uv never materialized)
  gemm_geglu256<<<dim3(64, 16), blk512, 0, stream>>>(
      x1b, w1T, w1T + 16777216, hbuf, 2048, 2048, 2048, 8192);
  // 9) fc = h @ w2
  gemm256<true><<<dim3(16, 16), blk512, 0, stream>>>(
      hbuf, w2T, fc, 8192, 8192, 8192, 2048);
  // 10) x2 = rmsnorm(x1 + fc) * n2w
  krms2<<<4096, blk, 0, stream>>>(x1b, fc, n2w, x2_out);
}